// Round 2
// baseline (358.088 us; speedup 1.0000x reference)
//
#include <hip/hip_runtime.h>
#include <cstdint>

typedef __attribute__((ext_vector_type(8))) __bf16 bf16x8;
typedef __attribute__((ext_vector_type(4))) float f32x4;

static constexpr int T_TOK = 4096;   // B*S
static constexpr int HDIM  = 1024;
static constexpr int NEXP  = 9;      // E_DYN + E_FIX
static constexpr int EDYN  = 8;
static constexpr int IDYN_ = 512;
static constexpr int IFIX_ = 2048;
static constexpr int CAPE  = 640;    // ceil(T/E_DYN*1.25) = 640 = 5*128

__device__ __forceinline__ unsigned short f2bf(float f) {
  unsigned u = __float_as_uint(f);
  u += 0x7fffu + ((u >> 16) & 1u);   // RNE
  return (unsigned short)(u >> 16);
}

__device__ __forceinline__ void gl_lds16(const void* g, void* l) {
  __builtin_amdgcn_global_load_lds((const __attribute__((address_space(1))) void*)g,
                                   (__attribute__((address_space(3))) void*)l,
                                   16, 0, 0);
}

// ---------------- fp32 -> bf16 conversion ----------------
__global__ void cvt_kernel(const float4* __restrict__ src, ushort4* __restrict__ dst, int n4) {
  int stride = gridDim.x * blockDim.x;
  for (int i = blockIdx.x * blockDim.x + threadIdx.x; i < n4; i += stride) {
    float4 f = src[i];
    dst[i] = make_ushort4(f2bf(f.x), f2bf(f.y), f2bf(f.z), f2bf(f.w));
  }
}

// ---------------- gating logits: full_logits = x @ gate_w.T (fp32) ----------------
__global__ __launch_bounds__(256)
void logits_kernel(const float* __restrict__ x, const float* __restrict__ gw,
                   float* __restrict__ logits) {
  int wave = threadIdx.x >> 6, lane = threadIdx.x & 63;
  int t = blockIdx.x * 4 + wave;
  if (t >= T_TOK) return;
  const float* xr = x + (size_t)t * HDIM;
  float acc[NEXP];
#pragma unroll
  for (int e = 0; e < NEXP; ++e) acc[e] = 0.f;
  for (int h = lane; h < HDIM; h += 64) {
    float xv = xr[h];
#pragma unroll
    for (int e = 0; e < NEXP; ++e) acc[e] += xv * gw[e * HDIM + h];
  }
#pragma unroll
  for (int e = 0; e < NEXP; ++e) {
    float v = acc[e];
#pragma unroll
    for (int off = 32; off > 0; off >>= 1) v += __shfl_down(v, off, 64);
    if (lane == 0) logits[t * NEXP + e] = v;
  }
}

// ---------------- per-token routing (top-p count + sparse mixer) ----------------
__global__ __launch_bounds__(256)
void routing_kernel(const float* __restrict__ logits, float* __restrict__ rw,
                    int* __restrict__ mask) {
  int t = blockIdx.x * blockDim.x + threadIdx.x;
  if (t >= T_TOK) return;
  float s[EDYN];
#pragma unroll
  for (int e = 0; e < EDYN; ++e) s[e] = logits[t * NEXP + e];

  // dyn_k via top-p over softmax(s)
  float m = s[0];
#pragma unroll
  for (int e = 1; e < EDYN; ++e) m = fmaxf(m, s[e]);
  float p[EDYN]; float psum = 0.f;
#pragma unroll
  for (int e = 0; e < EDYN; ++e) { p[e] = expf(s[e] - m); psum += p[e]; }
#pragma unroll
  for (int e = 0; e < EDYN; ++e) p[e] /= psum;
  float sp[EDYN];
#pragma unroll
  for (int e = 0; e < EDYN; ++e) sp[e] = p[e];
  for (int i = 1; i < EDYN; ++i) {            // insertion sort descending
    float key = sp[i]; int j = i - 1;
    while (j >= 0 && sp[j] < key) { sp[j + 1] = sp[j]; --j; }
    sp[j + 1] = key;
  }
  float c = 0.f; int cnt = 0;
#pragma unroll
  for (int e = 0; e < EDYN; ++e) { c += sp[e]; cnt += (c < 0.75f) ? 1 : 0; }
  int dyn_k = cnt + 1; if (dyn_k > 4) dyn_k = 4;

  // sparse mixer (TOP_K=4 iterations)
  float ms[EDYN];
#pragma unroll
  for (int e = 0; e < EDYN; ++e) ms[e] = s[e];
  float mult[4]; int sel[4];
  for (int k = 0; k < 4; ++k) {
    float thr = ms[0]; int am = 0;
#pragma unroll
    for (int e = 1; e < EDYN; ++e) if (ms[e] > thr) { thr = ms[e]; am = e; }
    float vals[EDYN]; float mx = -INFINITY;
#pragma unroll
    for (int e = 0; e < EDYN; ++e) {
      float factor = fmaxf(fabsf(s[e]), fabsf(thr));
      float ratio = (thr - s[e]) / factor;          // NaN (0/0) compares false
      float v = (ratio > 0.2f) ? -INFINITY : ms[e];
      vals[e] = v; mx = fmaxf(mx, v);
    }
    float sum = 0.f;
#pragma unroll
    for (int e = 0; e < EDYN; ++e) sum += expf(vals[e] - mx);
    mult[k] = expf(vals[am] - mx) / sum;
    sel[k] = am;
    ms[am] = -INFINITY;
  }
  float r[EDYN];
#pragma unroll
  for (int e = 0; e < EDYN; ++e) r[e] = 0.f;
  for (int k = 0; k < 4; ++k) if (k < dyn_k) r[sel[k]] += mult[k];
  float ssum = 0.f;
#pragma unroll
  for (int e = 0; e < EDYN; ++e) ssum += r[e];
#pragma unroll
  for (int e = 0; e < EDYN; ++e) {
    float v = r[e] / ssum;
    rw[t * EDYN + e] = v;
    mask[t * EDYN + e] = (v > 0.f) ? 1 : 0;
  }
}

// ---------------- capacity: per-expert prefix over tokens + compact token lists ----------------
__global__ void capacity_kernel(int* __restrict__ mask, int* __restrict__ tok,
                                int* __restrict__ counts) {
  int e = threadIdx.x >> 6;
  int lane = threadIdx.x & 63;
  int base = 0;
  for (int cIt = 0; cIt < T_TOK / 64; ++cIt) {
    int t = cIt * 64 + lane;
    int bit = mask[t * EDYN + e] != 0;
    unsigned long long bal = __ballot(bit);
    int prefix = __popcll(bal & ((1ull << lane) - 1ull));
    int cum = base + prefix + 1;
    int keep = bit && (cum <= CAPE);
    if (keep) tok[e * CAPE + (cum - 1)] = t;
    mask[t * EDYN + e] = keep;
    base += __popcll(bal);
  }
  int cnt = base < CAPE ? base : CAPE;
  if (lane == 0) counts[e] = cnt;
  for (int r = cnt + lane; r < CAPE; r += 64) tok[e * CAPE + r] = 0;  // pad
}

// ---------------- final gate: masked softmax over 9, global weights ----------------
__global__ __launch_bounds__(256)
void final_gate_kernel(const float* __restrict__ logits, const int* __restrict__ mask,
                       const float* __restrict__ rw, float* __restrict__ gdyn,
                       float* __restrict__ wsh) {
  int t = blockIdx.x * blockDim.x + threadIdx.x;
  if (t >= T_TOK) return;
  float vals[NEXP]; float mx = -INFINITY;
  int mk[EDYN];
#pragma unroll
  for (int e = 0; e < EDYN; ++e) {
    mk[e] = mask[t * EDYN + e];
    vals[e] = mk[e] ? logits[t * NEXP + e] : -INFINITY;
    mx = fmaxf(mx, vals[e]);
  }
  vals[EDYN] = logits[t * NEXP + EDYN];
  mx = fmaxf(mx, vals[EDYN]);
  float ex[NEXP]; float sum = 0.f;
#pragma unroll
  for (int e = 0; e < NEXP; ++e) { ex[e] = expf(vals[e] - mx); sum += ex[e]; }
  float inv = 1.f / sum;
  float sd = 0.f;
#pragma unroll
  for (int e = 0; e < EDYN; ++e) sd += ex[e] * inv;
#pragma unroll
  for (int e = 0; e < EDYN; ++e)
    gdyn[t * EDYN + e] = mk[e] ? rw[t * EDYN + e] * sd : 0.f;
  wsh[t] = ex[EDYN] * inv;
}

// ---------------- per-list-entry weights ----------------
__global__ void fill_wlist_kernel(const int* __restrict__ tok, const int* __restrict__ counts,
                                  const float* __restrict__ gdyn, float* __restrict__ wlist) {
  int i = blockIdx.x * blockDim.x + threadIdx.x;
  if (i >= EDYN * CAPE) return;
  int e = i / CAPE, r = i % CAPE;
  wlist[i] = (r < counts[e]) ? gdyn[tok[i] * EDYN + e] : 0.f;
}

// ---------------- fused gate+up GEMM with SiLU epilogue ----------------
// BM=128, BN=64, BK=64; 4 waves 2x2, each 64x32; A row-major TxK, W row-major NxK (B^T)
template <bool GATHER>
__global__ __launch_bounds__(256)
void gemm_gateup_kernel(const unsigned short* __restrict__ xb,
                        const unsigned short* __restrict__ Wg,
                        const unsigned short* __restrict__ Wu,
                        unsigned short* __restrict__ act,
                        const int* __restrict__ toklist,
                        const int* __restrict__ counts,
                        int N, int K, int Mstride) {
  const int e = blockIdx.z;
  const int m0 = blockIdx.x * 128;
  const int n0 = blockIdx.y * 64;
  if (GATHER) { if (m0 >= counts[e]) return; }

  const unsigned short* Wg_e = Wg + (size_t)e * N * K;
  const unsigned short* Wu_e = Wu + (size_t)e * N * K;
  unsigned short* act_e = act + (size_t)e * Mstride * N;
  const int* tok_e = toklist + e * CAPE;

  __shared__ __align__(16) unsigned short As[128 * 64];
  __shared__ __align__(16) unsigned short Bgs[64 * 64];
  __shared__ __align__(16) unsigned short Bus[64 * 64];

  const int tid = threadIdx.x;
  const int lane = tid & 63;
  const int wave = tid >> 6;
  const int wr = wave >> 1, wc = wave & 1;
  const int srow = tid >> 3;
  const int scol = (tid & 7) * 8;

  const unsigned short* a_src[4];
#pragma unroll
  for (int it = 0; it < 4; ++it) {
    int r = m0 + it * 32 + srow;
    int ridx = GATHER ? tok_e[r] : r;
    a_src[it] = xb + (size_t)ridx * K + scol;
  }
  const unsigned short* bg_src[2]; const unsigned short* bu_src[2];
#pragma unroll
  for (int it = 0; it < 2; ++it) {
    int r = n0 + it * 32 + srow;
    bg_src[it] = Wg_e + (size_t)r * K + scol;
    bu_src[it] = Wu_e + (size_t)r * K + scol;
  }

  f32x4 accg[4][2], accu[4][2];
#pragma unroll
  for (int i = 0; i < 4; ++i)
#pragma unroll
    for (int j = 0; j < 2; ++j) {
      f32x4 z = {0.f, 0.f, 0.f, 0.f};
      accg[i][j] = z; accu[i][j] = z;
    }

  for (int kt = 0; kt < K; kt += 64) {
#pragma unroll
    for (int it = 0; it < 4; ++it)
      gl_lds16(a_src[it] + kt, &As[it * 2048 + wave * 512]);
#pragma unroll
    for (int it = 0; it < 2; ++it) {
      gl_lds16(bg_src[it] + kt, &Bgs[it * 2048 + wave * 512]);
      gl_lds16(bu_src[it] + kt, &Bus[it * 2048 + wave * 512]);
    }
    __syncthreads();
#pragma unroll
    for (int kk = 0; kk < 2; ++kk) {
      const int ko = kk * 32 + (lane >> 4) * 8;
      bf16x8 a[4], bg[2], bu[2];
#pragma unroll
      for (int mi = 0; mi < 4; ++mi)
        a[mi] = *reinterpret_cast<const bf16x8*>(&As[(wr * 64 + mi * 16 + (lane & 15)) * 64 + ko]);
#pragma unroll
      for (int ni = 0; ni < 2; ++ni) {
        bg[ni] = *reinterpret_cast<const bf16x8*>(&Bgs[(wc * 32 + ni * 16 + (lane & 15)) * 64 + ko]);
        bu[ni] = *reinterpret_cast<const bf16x8*>(&Bus[(wc * 32 + ni * 16 + (lane & 15)) * 64 + ko]);
      }
#pragma unroll
      for (int mi = 0; mi < 4; ++mi)
#pragma unroll
        for (int ni = 0; ni < 2; ++ni) {
          accg[mi][ni] = __builtin_amdgcn_mfma_f32_16x16x32_bf16(a[mi], bg[ni], accg[mi][ni], 0, 0, 0);
          accu[mi][ni] = __builtin_amdgcn_mfma_f32_16x16x32_bf16(a[mi], bu[ni], accu[mi][ni], 0, 0, 0);
        }
    }
    __syncthreads();
  }

#pragma unroll
  for (int mi = 0; mi < 4; ++mi)
#pragma unroll
    for (int ni = 0; ni < 2; ++ni)
#pragma unroll
      for (int j = 0; j < 4; ++j) {
        int row = m0 + wr * 64 + mi * 16 + (lane >> 4) * 4 + j;
        int col = n0 + wc * 32 + ni * 16 + (lane & 15);
        float g = accg[mi][ni][j], u = accu[mi][ni][j];
        float v = (g / (1.f + __expf(-g))) * u;   // silu(g)*u
        act_e[(size_t)row * N + col] = f2bf(v);
      }
}

// ---------------- down GEMM ----------------
// BM=128, BN=128, BK=64; 4 waves 2x2, each 64x64
template <bool DYN>
__global__ __launch_bounds__(256)
void gemm_down_kernel(const unsigned short* __restrict__ act,
                      const unsigned short* __restrict__ Wd,
                      float* __restrict__ out,
                      const int* __restrict__ toklist,
                      const int* __restrict__ counts,
                      const float* __restrict__ wlist,
                      const float* __restrict__ wsh,
                      int N, int K, int Mstride) {
  const int e = blockIdx.z;
  const int m0 = blockIdx.x * 128;
  const int n0 = blockIdx.y * 128;
  if (DYN) { if (m0 >= counts[e]) return; }

  const unsigned short* A_e = act + (size_t)e * Mstride * K;
  const unsigned short* Wd_e = Wd + (size_t)e * N * K;

  __shared__ __align__(16) unsigned short As[128 * 64];
  __shared__ __align__(16) unsigned short Bs[128 * 64];

  const int tid = threadIdx.x;
  const int lane = tid & 63;
  const int wave = tid >> 6;
  const int wr = wave >> 1, wc = wave & 1;
  const int srow = tid >> 3;
  const int scol = (tid & 7) * 8;

  const unsigned short* a_src[4]; const unsigned short* b_src[4];
#pragma unroll
  for (int it = 0; it < 4; ++it) {
    a_src[it] = A_e + (size_t)(m0 + it * 32 + srow) * K + scol;
    b_src[it] = Wd_e + (size_t)(n0 + it * 32 + srow) * K + scol;
  }

  f32x4 acc[4][4];
#pragma unroll
  for (int i = 0; i < 4; ++i)
#pragma unroll
    for (int j = 0; j < 4; ++j) { f32x4 z = {0.f, 0.f, 0.f, 0.f}; acc[i][j] = z; }

  for (int kt = 0; kt < K; kt += 64) {
#pragma unroll
    for (int it = 0; it < 4; ++it) {
      gl_lds16(a_src[it] + kt, &As[it * 2048 + wave * 512]);
      gl_lds16(b_src[it] + kt, &Bs[it * 2048 + wave * 512]);
    }
    __syncthreads();
#pragma unroll
    for (int kk = 0; kk < 2; ++kk) {
      const int ko = kk * 32 + (lane >> 4) * 8;
      bf16x8 a[4], b[4];
#pragma unroll
      for (int mi = 0; mi < 4; ++mi)
        a[mi] = *reinterpret_cast<const bf16x8*>(&As[(wr * 64 + mi * 16 + (lane & 15)) * 64 + ko]);
#pragma unroll
      for (int ni = 0; ni < 4; ++ni)
        b[ni] = *reinterpret_cast<const bf16x8*>(&Bs[(wc * 64 + ni * 16 + (lane & 15)) * 64 + ko]);
#pragma unroll
      for (int mi = 0; mi < 4; ++mi)
#pragma unroll
        for (int ni = 0; ni < 4; ++ni)
          acc[mi][ni] = __builtin_amdgcn_mfma_f32_16x16x32_bf16(a[mi], b[ni], acc[mi][ni], 0, 0, 0);
    }
    __syncthreads();
  }

#pragma unroll
  for (int mi = 0; mi < 4; ++mi)
#pragma unroll
    for (int ni = 0; ni < 4; ++ni)
#pragma unroll
      for (int j = 0; j < 4; ++j) {
        int row = m0 + wr * 64 + mi * 16 + (lane >> 4) * 4 + j;
        int col = n0 + wc * 64 + ni * 16 + (lane & 15);
        float v = acc[mi][ni][j];
        if (DYN) {
          float w = wlist[e * CAPE + row];
          if (w != 0.f)
            atomicAdd(&out[(size_t)toklist[e * CAPE + row] * HDIM + col], w * v);
        } else {
          out[(size_t)row * HDIM + col] = wsh[row] * v;  // runs before dyn adds
        }
      }
}

// ---------------- host ----------------
extern "C" void kernel_launch(void* const* d_in, const int* in_sizes, int n_in,
                              void* d_out, int out_size, void* d_ws, size_t ws_size,
                              hipStream_t stream) {
  const float* x   = (const float*)d_in[0];
  const float* gw  = (const float*)d_in[1];
  const float* wdg = (const float*)d_in[2];
  const float* wdu = (const float*)d_in[3];
  const float* wdd = (const float*)d_in[4];
  const float* wsg = (const float*)d_in[5];
  const float* wsu = (const float*)d_in[6];
  const float* wsd = (const float*)d_in[7];
  float* out = (float*)d_out;

  char* p = (char*)d_ws;
  auto alloc = [&](size_t bytes) {
    char* r = p; p += (bytes + 255) & ~(size_t)255; return r;
  };
  unsigned short* xb    = (unsigned short*)alloc((size_t)T_TOK * HDIM * 2);
  unsigned short* wdgb  = (unsigned short*)alloc((size_t)EDYN * IDYN_ * HDIM * 2);
  unsigned short* wdub  = (unsigned short*)alloc((size_t)EDYN * IDYN_ * HDIM * 2);
  unsigned short* wddb  = (unsigned short*)alloc((size_t)EDYN * HDIM * IDYN_ * 2);
  unsigned short* wsgb  = (unsigned short*)alloc((size_t)IFIX_ * HDIM * 2);
  unsigned short* wsub  = (unsigned short*)alloc((size_t)IFIX_ * HDIM * 2);
  unsigned short* wsdb  = (unsigned short*)alloc((size_t)HDIM * IFIX_ * 2);
  unsigned short* actsh = (unsigned short*)alloc((size_t)T_TOK * IFIX_ * 2);
  unsigned short* actdy = (unsigned short*)alloc((size_t)EDYN * CAPE * IDYN_ * 2);
  float* logits = (float*)alloc((size_t)T_TOK * NEXP * 4);
  float* rw     = (float*)alloc((size_t)T_TOK * EDYN * 4);
  int*   mask   = (int*)alloc((size_t)T_TOK * EDYN * 4);
  float* gdyn   = (float*)alloc((size_t)T_TOK * EDYN * 4);
  float* wshv   = (float*)alloc((size_t)T_TOK * 4);
  int*   counts = (int*)alloc(256);
  int*   tok    = (int*)alloc((size_t)EDYN * CAPE * 4);
  float* wlist  = (float*)alloc((size_t)EDYN * CAPE * 4);

  auto cvt = [&](const float* s, unsigned short* d, size_t n) {
    int n4 = (int)(n / 4);
    int blocks = (n4 + 255) / 256; if (blocks > 2048) blocks = 2048;
    cvt_kernel<<<dim3(blocks), dim3(256), 0, stream>>>((const float4*)s, (ushort4*)d, n4);
  };
  cvt(x,   xb,   (size_t)T_TOK * HDIM);
  cvt(wdg, wdgb, (size_t)EDYN * IDYN_ * HDIM);
  cvt(wdu, wdub, (size_t)EDYN * IDYN_ * HDIM);
  cvt(wdd, wddb, (size_t)EDYN * HDIM * IDYN_);
  cvt(wsg, wsgb, (size_t)IFIX_ * HDIM);
  cvt(wsu, wsub, (size_t)IFIX_ * HDIM);
  cvt(wsd, wsdb, (size_t)HDIM * IFIX_);

  logits_kernel<<<dim3(T_TOK / 4), dim3(256), 0, stream>>>(x, gw, logits);
  routing_kernel<<<dim3(T_TOK / 256), dim3(256), 0, stream>>>(logits, rw, mask);
  capacity_kernel<<<dim3(1), dim3(512), 0, stream>>>(mask, tok, counts);
  final_gate_kernel<<<dim3(T_TOK / 256), dim3(256), 0, stream>>>(logits, mask, rw, gdyn, wshv);
  fill_wlist_kernel<<<dim3((EDYN * CAPE) / 256), dim3(256), 0, stream>>>(tok, counts, gdyn, wlist);

  // shared expert (writes every out element) ...
  gemm_gateup_kernel<false><<<dim3(T_TOK / 128, IFIX_ / 64, 1), dim3(256), 0, stream>>>(
      xb, wsgb, wsub, actsh, tok, counts, IFIX_, HDIM, T_TOK);
  gemm_down_kernel<false><<<dim3(T_TOK / 128, HDIM / 128, 1), dim3(256), 0, stream>>>(
      actsh, wsdb, out, tok, counts, wlist, wshv, HDIM, IFIX_, T_TOK);
  // ... then dyn experts accumulate on top (stream-ordered after shared store)
  gemm_gateup_kernel<true><<<dim3(CAPE / 128, IDYN_ / 64, EDYN), dim3(256), 0, stream>>>(
      xb, wdgb, wdub, actdy, tok, counts, IDYN_, HDIM, CAPE);
  gemm_down_kernel<true><<<dim3(CAPE / 128, HDIM / 128, EDYN), dim3(256), 0, stream>>>(
      actdy, wddb, out, tok, counts, wlist, wshv, HDIM, IDYN_, CAPE);
}

// Round 4
// 348.144 us; speedup vs baseline: 1.0286x; 1.0286x over previous
//
#include <hip/hip_runtime.h>
#include <cstdint>

typedef __attribute__((ext_vector_type(8))) __bf16 bf16x8;
typedef __attribute__((ext_vector_type(4))) float f32x4;

static constexpr int T_TOK = 4096;   // B*S
static constexpr int HDIM  = 1024;
static constexpr int NEXP  = 9;      // E_DYN + E_FIX
static constexpr int EDYN  = 8;
static constexpr int IDYN_ = 512;
static constexpr int IFIX_ = 2048;
static constexpr int CAPE  = 640;    // ceil(T/E_DYN*1.25) = 640 = 5*128

__device__ __forceinline__ unsigned short f2bf(float f) {
  unsigned u = __float_as_uint(f);
  u += 0x7fffu + ((u >> 16) & 1u);   // RNE
  return (unsigned short)(u >> 16);
}

__device__ __forceinline__ void gl_lds16(const void* g, void* l) {
  __builtin_amdgcn_global_load_lds((const __attribute__((address_space(1))) void*)g,
                                   (__attribute__((address_space(3))) void*)l,
                                   16, 0, 0);
}

// bijective XCD-chunked swizzle (nwg % 8 == 0)
__device__ __forceinline__ int xcd_swz(int lin, int nwg) {
  int q = nwg >> 3;
  return (lin & 7) * q + (lin >> 3);
}

// ---------------- fused fp32 -> bf16 conversion (all 7 tensors, one launch) ----------------
static constexpr int C0 = 1048576;            // x        (4096*1024/4)
static constexpr int C1 = C0 + 1048576;       // dyn_gate (8*512*1024/4)
static constexpr int C2 = C1 + 1048576;       // dyn_up
static constexpr int C3 = C2 + 1048576;       // dyn_down
static constexpr int C4 = C3 + 524288;        // sh_gate  (2048*1024/4)
static constexpr int C5 = C4 + 524288;        // sh_up
static constexpr int C6 = C5 + 524288;        // sh_down
__global__ void cvt_all_kernel(const float4* __restrict__ s0, const float4* __restrict__ s1,
                               const float4* __restrict__ s2, const float4* __restrict__ s3,
                               const float4* __restrict__ s4, const float4* __restrict__ s5,
                               const float4* __restrict__ s6,
                               ushort4* __restrict__ d0, ushort4* __restrict__ d1,
                               ushort4* __restrict__ d2, ushort4* __restrict__ d3,
                               ushort4* __restrict__ d4, ushort4* __restrict__ d5,
                               ushort4* __restrict__ d6) {
  int stride = gridDim.x * blockDim.x;
  for (int i = blockIdx.x * blockDim.x + threadIdx.x; i < C6; i += stride) {
    const float4* s; ushort4* d; int off;
    if      (i < C0) { s = s0; d = d0; off = i; }
    else if (i < C1) { s = s1; d = d1; off = i - C0; }
    else if (i < C2) { s = s2; d = d2; off = i - C1; }
    else if (i < C3) { s = s3; d = d3; off = i - C2; }
    else if (i < C4) { s = s4; d = d4; off = i - C3; }
    else if (i < C5) { s = s5; d = d5; off = i - C4; }
    else             { s = s6; d = d6; off = i - C5; }
    float4 f = s[off];
    d[off] = make_ushort4(f2bf(f.x), f2bf(f.y), f2bf(f.z), f2bf(f.w));
  }
}

// ---------------- gating logits + per-token routing (fused) ----------------
__global__ __launch_bounds__(256)
void logits_routing_kernel(const float* __restrict__ x, const float* __restrict__ gw,
                           float* __restrict__ logits, float* __restrict__ rw,
                           int* __restrict__ mask) {
  int wave = threadIdx.x >> 6, lane = threadIdx.x & 63;
  int t = blockIdx.x * 4 + wave;
  if (t >= T_TOK) return;
  const float* xr = x + (size_t)t * HDIM;
  float acc[NEXP];
#pragma unroll
  for (int e = 0; e < NEXP; ++e) acc[e] = 0.f;
  for (int h = lane; h < HDIM; h += 64) {
    float xv = xr[h];
#pragma unroll
    for (int e = 0; e < NEXP; ++e) acc[e] += xv * gw[e * HDIM + h];
  }
#pragma unroll
  for (int e = 0; e < NEXP; ++e) {
    float v = acc[e];
#pragma unroll
    for (int off = 32; off > 0; off >>= 1) v += __shfl_down(v, off, 64);
    acc[e] = v;
  }
  if (lane != 0) return;
  float s[EDYN];
#pragma unroll
  for (int e = 0; e < NEXP; ++e) logits[t * NEXP + e] = acc[e];
#pragma unroll
  for (int e = 0; e < EDYN; ++e) s[e] = acc[e];

  // dyn_k via top-p over softmax(s)
  float m = s[0];
#pragma unroll
  for (int e = 1; e < EDYN; ++e) m = fmaxf(m, s[e]);
  float p[EDYN]; float psum = 0.f;
#pragma unroll
  for (int e = 0; e < EDYN; ++e) { p[e] = expf(s[e] - m); psum += p[e]; }
#pragma unroll
  for (int e = 0; e < EDYN; ++e) p[e] /= psum;
  float sp[EDYN];
#pragma unroll
  for (int e = 0; e < EDYN; ++e) sp[e] = p[e];
  for (int i = 1; i < EDYN; ++i) {            // insertion sort descending
    float key = sp[i]; int j = i - 1;
    while (j >= 0 && sp[j] < key) { sp[j + 1] = sp[j]; --j; }
    sp[j + 1] = key;
  }
  float c = 0.f; int cnt = 0;
#pragma unroll
  for (int e = 0; e < EDYN; ++e) { c += sp[e]; cnt += (c < 0.75f) ? 1 : 0; }
  int dyn_k = cnt + 1; if (dyn_k > 4) dyn_k = 4;

  // sparse mixer (TOP_K=4 iterations)
  float ms[EDYN];
#pragma unroll
  for (int e = 0; e < EDYN; ++e) ms[e] = s[e];
  float mult[4]; int sel[4];
  for (int k = 0; k < 4; ++k) {
    float thr = ms[0]; int am = 0;
#pragma unroll
    for (int e = 1; e < EDYN; ++e) if (ms[e] > thr) { thr = ms[e]; am = e; }
    float vals[EDYN]; float mx = -INFINITY;
#pragma unroll
    for (int e = 0; e < EDYN; ++e) {
      float factor = fmaxf(fabsf(s[e]), fabsf(thr));
      float ratio = (thr - s[e]) / factor;          // NaN (0/0) compares false
      float v = (ratio > 0.2f) ? -INFINITY : ms[e];
      vals[e] = v; mx = fmaxf(mx, v);
    }
    float sum = 0.f;
#pragma unroll
    for (int e = 0; e < EDYN; ++e) sum += expf(vals[e] - mx);
    mult[k] = expf(vals[am] - mx) / sum;
    sel[k] = am;
    ms[am] = -INFINITY;
  }
  float r[EDYN];
#pragma unroll
  for (int e = 0; e < EDYN; ++e) r[e] = 0.f;
  for (int k = 0; k < 4; ++k) if (k < dyn_k) r[sel[k]] += mult[k];
  float ssum = 0.f;
#pragma unroll
  for (int e = 0; e < EDYN; ++e) ssum += r[e];
#pragma unroll
  for (int e = 0; e < EDYN; ++e) {
    float v = r[e] / ssum;
    rw[t * EDYN + e] = v;
    mask[t * EDYN + e] = (v > 0.f) ? 1 : 0;
  }
}

// ---------------- capacity: parallel prefix-scan per expert ----------------
// one block per expert; 1024 threads; thread i owns tokens [4i, 4i+4)
__global__ __launch_bounds__(1024)
void capacity_kernel(int* __restrict__ mask, int* __restrict__ tok,
                     int* __restrict__ counts) {
  const int e = blockIdx.x;
  const int tid = threadIdx.x;
  const int lane = tid & 63, wave = tid >> 6;
  __shared__ int wsum[16];
  const int t0 = tid * 4;
  int bits[4]; int c = 0;
#pragma unroll
  for (int j = 0; j < 4; ++j) { bits[j] = mask[(t0 + j) * EDYN + e]; c += bits[j]; }
  int sc = c;                                  // inclusive wave scan
#pragma unroll
  for (int off = 1; off < 64; off <<= 1) {
    int v = __shfl_up(sc, off, 64);
    if (lane >= off) sc += v;
  }
  if (lane == 63) wsum[wave] = sc;
  __syncthreads();
  int wbase = 0;
  for (int w = 0; w < wave; ++w) wbase += wsum[w];
  int pos = wbase + sc - c;                    // exclusive prefix (token order)
#pragma unroll
  for (int j = 0; j < 4; ++j) {
    int keep = bits[j] && (pos < CAPE);
    if (keep) tok[e * CAPE + pos] = t0 + j;
    mask[(t0 + j) * EDYN + e] = keep;
    pos += bits[j];
  }
  int total = 0;
  for (int w = 0; w < 16; ++w) total += wsum[w];
  int cnt = total < CAPE ? total : CAPE;
  if (tid == 0) counts[e] = cnt;
  for (int r = cnt + tid; r < CAPE; r += 1024) tok[e * CAPE + r] = -1;  // pad sentinel
}

// ---------------- final gate: masked softmax over 9, global weights ----------------
__global__ __launch_bounds__(256)
void final_gate_kernel(const float* __restrict__ logits, const int* __restrict__ mask,
                       const float* __restrict__ rw, float* __restrict__ gdyn,
                       float* __restrict__ wsh) {
  int t = blockIdx.x * blockDim.x + threadIdx.x;
  if (t >= T_TOK) return;
  float vals[NEXP]; float mx = -INFINITY;
  int mk[EDYN];
#pragma unroll
  for (int e = 0; e < EDYN; ++e) {
    mk[e] = mask[t * EDYN + e];
    vals[e] = mk[e] ? logits[t * NEXP + e] : -INFINITY;
    mx = fmaxf(mx, vals[e]);
  }
  vals[EDYN] = logits[t * NEXP + EDYN];
  mx = fmaxf(mx, vals[EDYN]);
  float ex[NEXP]; float sum = 0.f;
#pragma unroll
  for (int e = 0; e < NEXP; ++e) { ex[e] = expf(vals[e] - mx); sum += ex[e]; }
  float inv = 1.f / sum;
  float sd = 0.f;
#pragma unroll
  for (int e = 0; e < EDYN; ++e) sd += ex[e] * inv;
#pragma unroll
  for (int e = 0; e < EDYN; ++e)
    gdyn[t * EDYN + e] = mk[e] ? rw[t * EDYN + e] * sd : 0.f;
  wsh[t] = ex[EDYN] * inv;
}

// ---------------- fused gate+up GEMM with SiLU epilogue ----------------
// BM=128, BN=64(x2), BK=64; 4 waves 2x2; A row-major TxK, W row-major NxK (B^T)
// nid is LINEARIZED tile index: m0 = (nid%MT)*128, n0 = (nid/MT)*64
template <bool GATHER>
__global__ __launch_bounds__(256)
void gemm_gateup_kernel(const unsigned short* __restrict__ xb,
                        const unsigned short* __restrict__ Wg,
                        const unsigned short* __restrict__ Wu,
                        unsigned short* __restrict__ act,
                        const int* __restrict__ toklist,
                        const int* __restrict__ counts,
                        int N, int K, int Mstride, int MT) {
  const int e = blockIdx.z;
  int nid = blockIdx.x;
  if (!GATHER) nid = xcd_swz(nid, gridDim.x);
  const int m0 = (nid % MT) * 128;
  const int n0 = (nid / MT) * 64;
  if (GATHER) { if (m0 >= counts[e]) return; }

  const unsigned short* Wg_e = Wg + (size_t)e * N * K;
  const unsigned short* Wu_e = Wu + (size_t)e * N * K;
  unsigned short* act_e = act + (size_t)e * Mstride * N;
  const int* tok_e = toklist + e * CAPE;

  __shared__ __align__(16) unsigned short As[128 * 64];
  __shared__ __align__(16) unsigned short Bgs[64 * 64];
  __shared__ __align__(16) unsigned short Bus[64 * 64];

  const int tid = threadIdx.x;
  const int lane = tid & 63;
  const int wave = tid >> 6;
  const int wr = wave >> 1, wc = wave & 1;
  const int srow = tid >> 3;
  const int scol = (tid & 7) * 8;

  const unsigned short* a_src[4];
#pragma unroll
  for (int it = 0; it < 4; ++it) {
    int r = m0 + it * 32 + srow;
    int ridx = r;
    if (GATHER) { int tv = tok_e[r]; ridx = tv < 0 ? 0 : tv; }
    a_src[it] = xb + (size_t)ridx * K + scol;
  }
  const unsigned short* bg_src[2]; const unsigned short* bu_src[2];
#pragma unroll
  for (int it = 0; it < 2; ++it) {
    int r = n0 + it * 32 + srow;
    bg_src[it] = Wg_e + (size_t)r * K + scol;
    bu_src[it] = Wu_e + (size_t)r * K + scol;
  }

  f32x4 accg[4][2], accu[4][2];
#pragma unroll
  for (int i = 0; i < 4; ++i)
#pragma unroll
    for (int j = 0; j < 2; ++j) {
      f32x4 z = {0.f, 0.f, 0.f, 0.f};
      accg[i][j] = z; accu[i][j] = z;
    }

  for (int kt = 0; kt < K; kt += 64) {
#pragma unroll
    for (int it = 0; it < 4; ++it)
      gl_lds16(a_src[it] + kt, &As[it * 2048 + wave * 512]);
#pragma unroll
    for (int it = 0; it < 2; ++it) {
      gl_lds16(bg_src[it] + kt, &Bgs[it * 2048 + wave * 512]);
      gl_lds16(bu_src[it] + kt, &Bus[it * 2048 + wave * 512]);
    }
    __syncthreads();
#pragma unroll
    for (int kk = 0; kk < 2; ++kk) {
      const int ko = kk * 32 + (lane >> 4) * 8;
      bf16x8 a[4], bg[2], bu[2];
#pragma unroll
      for (int mi = 0; mi < 4; ++mi)
        a[mi] = *reinterpret_cast<const bf16x8*>(&As[(wr * 64 + mi * 16 + (lane & 15)) * 64 + ko]);
#pragma unroll
      for (int ni = 0; ni < 2; ++ni) {
        bg[ni] = *reinterpret_cast<const bf16x8*>(&Bgs[(wc * 32 + ni * 16 + (lane & 15)) * 64 + ko]);
        bu[ni] = *reinterpret_cast<const bf16x8*>(&Bus[(wc * 32 + ni * 16 + (lane & 15)) * 64 + ko]);
      }
#pragma unroll
      for (int mi = 0; mi < 4; ++mi)
#pragma unroll
        for (int ni = 0; ni < 2; ++ni) {
          accg[mi][ni] = __builtin_amdgcn_mfma_f32_16x16x32_bf16(a[mi], bg[ni], accg[mi][ni], 0, 0, 0);
          accu[mi][ni] = __builtin_amdgcn_mfma_f32_16x16x32_bf16(a[mi], bu[ni], accu[mi][ni], 0, 0, 0);
        }
    }
    __syncthreads();
  }

#pragma unroll
  for (int mi = 0; mi < 4; ++mi)
#pragma unroll
    for (int ni = 0; ni < 2; ++ni)
#pragma unroll
      for (int j = 0; j < 4; ++j) {
        int row = m0 + wr * 64 + mi * 16 + (lane >> 4) * 4 + j;
        int col = n0 + wc * 32 + ni * 16 + (lane & 15);
        float g = accg[mi][ni][j], u = accu[mi][ni][j];
        float v = (g / (1.f + __expf(-g))) * u;   // silu(g)*u
        act_e[(size_t)row * N + col] = f2bf(v);
      }
}

// ---------------- down GEMM ----------------
// BM=128, BN=128, BK=64; 4 waves 2x2, each 64x64
// nid LINEARIZED: m0 = (nid%MT)*128, n0 = (nid/MT)*128
template <bool DYN>
__global__ __launch_bounds__(256)
void gemm_down_kernel(const unsigned short* __restrict__ act,
                      const unsigned short* __restrict__ Wd,
                      float* __restrict__ out,
                      const int* __restrict__ toklist,
                      const int* __restrict__ counts,
                      const float* __restrict__ gdyn,
                      const float* __restrict__ wsh,
                      int N, int K, int Mstride, int MT) {
  const int e = blockIdx.z;
  int nid = blockIdx.x;
  if (!DYN) nid = xcd_swz(nid, gridDim.x);
  const int m0 = (nid % MT) * 128;
  const int n0 = (nid / MT) * 128;
  if (DYN) { if (m0 >= counts[e]) return; }

  const unsigned short* A_e = act + (size_t)e * Mstride * K;
  const unsigned short* Wd_e = Wd + (size_t)e * N * K;

  __shared__ __align__(16) unsigned short As[128 * 64];
  __shared__ __align__(16) unsigned short Bs[128 * 64];

  const int tid = threadIdx.x;
  const int lane = tid & 63;
  const int wave = tid >> 6;
  const int wr = wave >> 1, wc = wave & 1;
  const int srow = tid >> 3;
  const int scol = (tid & 7) * 8;

  const unsigned short* a_src[4]; const unsigned short* b_src[4];
#pragma unroll
  for (int it = 0; it < 4; ++it) {
    a_src[it] = A_e + (size_t)(m0 + it * 32 + srow) * K + scol;
    b_src[it] = Wd_e + (size_t)(n0 + it * 32 + srow) * K + scol;
  }

  f32x4 acc[4][4];
#pragma unroll
  for (int i = 0; i < 4; ++i)
#pragma unroll
    for (int j = 0; j < 4; ++j) { f32x4 z = {0.f, 0.f, 0.f, 0.f}; acc[i][j] = z; }

  for (int kt = 0; kt < K; kt += 64) {
#pragma unroll
    for (int it = 0; it < 4; ++it) {
      gl_lds16(a_src[it] + kt, &As[it * 2048 + wave * 512]);
      gl_lds16(b_src[it] + kt, &Bs[it * 2048 + wave * 512]);
    }
    __syncthreads();
#pragma unroll
    for (int kk = 0; kk < 2; ++kk) {
      const int ko = kk * 32 + (lane >> 4) * 8;
      bf16x8 a[4], b[4];
#pragma unroll
      for (int mi = 0; mi < 4; ++mi)
        a[mi] = *reinterpret_cast<const bf16x8*>(&As[(wr * 64 + mi * 16 + (lane & 15)) * 64 + ko]);
#pragma unroll
      for (int ni = 0; ni < 4; ++ni)
        b[ni] = *reinterpret_cast<const bf16x8*>(&Bs[(wc * 64 + ni * 16 + (lane & 15)) * 64 + ko]);
#pragma unroll
      for (int mi = 0; mi < 4; ++mi)
#pragma unroll
        for (int ni = 0; ni < 4; ++ni)
          acc[mi][ni] = __builtin_amdgcn_mfma_f32_16x16x32_bf16(a[mi], b[ni], acc[mi][ni], 0, 0, 0);
    }
    __syncthreads();
  }

#pragma unroll
  for (int mi = 0; mi < 4; ++mi)
#pragma unroll
    for (int ni = 0; ni < 4; ++ni)
#pragma unroll
      for (int j = 0; j < 4; ++j) {
        int row = m0 + wr * 64 + mi * 16 + (lane >> 4) * 4 + j;
        int col = n0 + wc * 64 + ni * 16 + (lane & 15);
        float v = acc[mi][ni][j];
        if (DYN) {
          int t = toklist[e * CAPE + row];
          if (t >= 0)
            atomicAdd(&out[(size_t)t * HDIM + col], gdyn[t * EDYN + e] * v);
        } else {
          out[(size_t)row * HDIM + col] = wsh[row] * v;  // runs before dyn adds
        }
      }
}

// ---------------- host ----------------
extern "C" void kernel_launch(void* const* d_in, const int* in_sizes, int n_in,
                              void* d_out, int out_size, void* d_ws, size_t ws_size,
                              hipStream_t stream) {
  const float* x   = (const float*)d_in[0];
  const float* gw  = (const float*)d_in[1];
  const float* wdg = (const float*)d_in[2];
  const float* wdu = (const float*)d_in[3];
  const float* wdd = (const float*)d_in[4];
  const float* wsg = (const float*)d_in[5];
  const float* wsu = (const float*)d_in[6];
  const float* wsd = (const float*)d_in[7];
  float* out = (float*)d_out;

  char* p = (char*)d_ws;
  auto alloc = [&](size_t bytes) {
    char* r = p; p += (bytes + 255) & ~(size_t)255; return r;
  };
  unsigned short* xb    = (unsigned short*)alloc((size_t)T_TOK * HDIM * 2);
  unsigned short* wdgb  = (unsigned short*)alloc((size_t)EDYN * IDYN_ * HDIM * 2);
  unsigned short* wdub  = (unsigned short*)alloc((size_t)EDYN * IDYN_ * HDIM * 2);
  unsigned short* wddb  = (unsigned short*)alloc((size_t)EDYN * HDIM * IDYN_ * 2);
  unsigned short* wsgb  = (unsigned short*)alloc((size_t)IFIX_ * HDIM * 2);
  unsigned short* wsub  = (unsigned short*)alloc((size_t)IFIX_ * HDIM * 2);
  unsigned short* wsdb  = (unsigned short*)alloc((size_t)HDIM * IFIX_ * 2);
  unsigned short* actsh = (unsigned short*)alloc((size_t)T_TOK * IFIX_ * 2);
  unsigned short* actdy = (unsigned short*)alloc((size_t)EDYN * CAPE * IDYN_ * 2);
  float* logits = (float*)alloc((size_t)T_TOK * NEXP * 4);
  float* rw     = (float*)alloc((size_t)T_TOK * EDYN * 4);
  int*   mask   = (int*)alloc((size_t)T_TOK * EDYN * 4);
  float* gdyn   = (float*)alloc((size_t)T_TOK * EDYN * 4);
  float* wshv   = (float*)alloc((size_t)T_TOK * 4);
  int*   counts = (int*)alloc(256);
  int*   tok    = (int*)alloc((size_t)EDYN * CAPE * 4);

  cvt_all_kernel<<<dim3(2048), dim3(256), 0, stream>>>(
      (const float4*)x, (const float4*)wdg, (const float4*)wdu, (const float4*)wdd,
      (const float4*)wsg, (const float4*)wsu, (const float4*)wsd,
      (ushort4*)xb, (ushort4*)wdgb, (ushort4*)wdub, (ushort4*)wddb,
      (ushort4*)wsgb, (ushort4*)wsub, (ushort4*)wsdb);

  logits_routing_kernel<<<dim3(T_TOK / 4), dim3(256), 0, stream>>>(x, gw, logits, rw, mask);
  capacity_kernel<<<dim3(EDYN), dim3(1024), 0, stream>>>(mask, tok, counts);
  final_gate_kernel<<<dim3(T_TOK / 256), dim3(256), 0, stream>>>(logits, mask, rw, gdyn, wshv);

  // shared expert (writes every out element) ...
  gemm_gateup_kernel<false><<<dim3((T_TOK / 128) * (IFIX_ / 64), 1, 1), dim3(256), 0, stream>>>(
      xb, wsgb, wsub, actsh, tok, counts, IFIX_, HDIM, T_TOK, T_TOK / 128);
  gemm_down_kernel<false><<<dim3((T_TOK / 128) * (HDIM / 128), 1, 1), dim3(256), 0, stream>>>(
      actsh, wsdb, out, tok, counts, gdyn, wshv, HDIM, IFIX_, T_TOK, T_TOK / 128);
  // ... then dyn experts accumulate on top (stream-ordered after shared store)
  // LINEARIZED grid.x = MT*NT (fix for round-3 bug: kernel ignores blockIdx.y)
  gemm_gateup_kernel<true><<<dim3((CAPE / 128) * (IDYN_ / 64), 1, EDYN), dim3(256), 0, stream>>>(
      xb, wdgb, wdub, actdy, tok, counts, IDYN_, HDIM, CAPE, CAPE / 128);
  gemm_down_kernel<true><<<dim3((CAPE / 128) * (HDIM / 128), 1, EDYN), dim3(256), 0, stream>>>(
      actdy, wddb, out, tok, counts, gdyn, wshv, HDIM, IDYN_, CAPE, CAPE / 128);
}

// Round 5
// 334.626 us; speedup vs baseline: 1.0701x; 1.0404x over previous
//
#include <hip/hip_runtime.h>
#include <cstdint>

typedef __attribute__((ext_vector_type(8))) __bf16 bf16x8;
typedef __attribute__((ext_vector_type(4))) float f32x4;

static constexpr int T_TOK = 4096;   // B*S
static constexpr int HDIM  = 1024;
static constexpr int NEXP  = 9;      // E_DYN + E_FIX
static constexpr int EDYN  = 8;
static constexpr int IDYN_ = 512;
static constexpr int IFIX_ = 2048;
static constexpr int CAPE  = 640;    // ceil(T/E_DYN*1.25) = 640 = 5*128

__device__ __forceinline__ unsigned short f2bf(float f) {
  unsigned u = __float_as_uint(f);
  u += 0x7fffu + ((u >> 16) & 1u);   // RNE
  return (unsigned short)(u >> 16);
}

__device__ __forceinline__ void gl_lds16(const void* g, void* l) {
  __builtin_amdgcn_global_load_lds((const __attribute__((address_space(1))) void*)g,
                                   (__attribute__((address_space(3))) void*)l,
                                   16, 0, 0);
}

// ---------------- fused fp32 -> bf16 conversion (6 weight tensors) ----------------
static constexpr int D0 = 1048576;            // dyn_gate (8*512*1024/4)
static constexpr int D1 = D0 + 1048576;       // dyn_up
static constexpr int D2 = D1 + 1048576;       // dyn_down
static constexpr int D3 = D2 + 524288;        // sh_gate  (2048*1024/4)
static constexpr int D4 = D3 + 524288;        // sh_up
static constexpr int D5 = D4 + 524288;        // sh_down
__global__ void cvt_all_kernel(const float4* __restrict__ s1,
                               const float4* __restrict__ s2, const float4* __restrict__ s3,
                               const float4* __restrict__ s4, const float4* __restrict__ s5,
                               const float4* __restrict__ s6,
                               ushort4* __restrict__ d1,
                               ushort4* __restrict__ d2, ushort4* __restrict__ d3,
                               ushort4* __restrict__ d4, ushort4* __restrict__ d5,
                               ushort4* __restrict__ d6) {
  int stride = gridDim.x * blockDim.x;
  for (int i = blockIdx.x * blockDim.x + threadIdx.x; i < D5; i += stride) {
    const float4* s; ushort4* d; int off;
    if      (i < D0) { s = s1; d = d1; off = i; }
    else if (i < D1) { s = s2; d = d2; off = i - D0; }
    else if (i < D2) { s = s3; d = d3; off = i - D1; }
    else if (i < D3) { s = s4; d = d4; off = i - D2; }
    else if (i < D4) { s = s5; d = d5; off = i - D3; }
    else             { s = s6; d = d6; off = i - D4; }
    float4 f = s[off];
    d[off] = make_ushort4(f2bf(f.x), f2bf(f.y), f2bf(f.z), f2bf(f.w));
  }
}

// ---------------- gating logits + routing + x->bf16 (fused) ----------------
// one wave per token; lane owns h in {lane*8..+8} and {512+lane*8..+8}
__global__ __launch_bounds__(256)
void logits_routing_kernel(const float* __restrict__ x, const float* __restrict__ gw,
                           unsigned short* __restrict__ xb,
                           float* __restrict__ logits, float* __restrict__ rw,
                           int* __restrict__ mask) {
  int wave = threadIdx.x >> 6, lane = threadIdx.x & 63;
  int t = blockIdx.x * 4 + wave;
  if (t >= T_TOK) return;
  const float* xr = x + (size_t)t * HDIM;
  float acc[NEXP];
#pragma unroll
  for (int e = 0; e < NEXP; ++e) acc[e] = 0.f;
#pragma unroll
  for (int half = 0; half < 2; ++half) {
    const int h0 = half * 512 + lane * 8;
    float4 a = *(const float4*)(xr + h0);
    float4 b = *(const float4*)(xr + h0 + 4);
    float v[8] = {a.x, a.y, a.z, a.w, b.x, b.y, b.z, b.w};
    union { unsigned short us[8]; uint4 u4; } pk;
#pragma unroll
    for (int j = 0; j < 8; ++j) pk.us[j] = f2bf(v[j]);
    *(uint4*)(xb + (size_t)t * HDIM + h0) = pk.u4;   // coalesced 16B/lane
#pragma unroll
    for (int e = 0; e < NEXP; ++e) {
      float s = 0.f;
#pragma unroll
      for (int j = 0; j < 8; ++j) s += v[j] * gw[e * HDIM + h0 + j];
      acc[e] += s;
    }
  }
#pragma unroll
  for (int e = 0; e < NEXP; ++e) {
    float v = acc[e];
#pragma unroll
    for (int off = 32; off > 0; off >>= 1) v += __shfl_down(v, off, 64);
    acc[e] = v;
  }
  if (lane != 0) return;
  float s[EDYN];
#pragma unroll
  for (int e = 0; e < NEXP; ++e) logits[t * NEXP + e] = acc[e];
#pragma unroll
  for (int e = 0; e < EDYN; ++e) s[e] = acc[e];

  // dyn_k via top-p over softmax(s)
  float m = s[0];
#pragma unroll
  for (int e = 1; e < EDYN; ++e) m = fmaxf(m, s[e]);
  float p[EDYN]; float psum = 0.f;
#pragma unroll
  for (int e = 0; e < EDYN; ++e) { p[e] = expf(s[e] - m); psum += p[e]; }
#pragma unroll
  for (int e = 0; e < EDYN; ++e) p[e] /= psum;
  float sp[EDYN];
#pragma unroll
  for (int e = 0; e < EDYN; ++e) sp[e] = p[e];
  for (int i = 1; i < EDYN; ++i) {            // insertion sort descending
    float key = sp[i]; int j = i - 1;
    while (j >= 0 && sp[j] < key) { sp[j + 1] = sp[j]; --j; }
    sp[j + 1] = key;
  }
  float c = 0.f; int cnt = 0;
#pragma unroll
  for (int e = 0; e < EDYN; ++e) { c += sp[e]; cnt += (c < 0.75f) ? 1 : 0; }
  int dyn_k = cnt + 1; if (dyn_k > 4) dyn_k = 4;

  // sparse mixer (TOP_K=4 iterations)
  float ms[EDYN];
#pragma unroll
  for (int e = 0; e < EDYN; ++e) ms[e] = s[e];
  float mult[4]; int sel[4];
  for (int k = 0; k < 4; ++k) {
    float thr = ms[0]; int am = 0;
#pragma unroll
    for (int e = 1; e < EDYN; ++e) if (ms[e] > thr) { thr = ms[e]; am = e; }
    float vals[EDYN]; float mx = -INFINITY;
#pragma unroll
    for (int e = 0; e < EDYN; ++e) {
      float factor = fmaxf(fabsf(s[e]), fabsf(thr));
      float ratio = (thr - s[e]) / factor;          // NaN (0/0) compares false
      float v = (ratio > 0.2f) ? -INFINITY : ms[e];
      vals[e] = v; mx = fmaxf(mx, v);
    }
    float sum = 0.f;
#pragma unroll
    for (int e = 0; e < EDYN; ++e) sum += expf(vals[e] - mx);
    mult[k] = expf(vals[am] - mx) / sum;
    sel[k] = am;
    ms[am] = -INFINITY;
  }
  float r[EDYN];
#pragma unroll
  for (int e = 0; e < EDYN; ++e) r[e] = 0.f;
  for (int k = 0; k < 4; ++k) if (k < dyn_k) r[sel[k]] += mult[k];
  float ssum = 0.f;
#pragma unroll
  for (int e = 0; e < EDYN; ++e) ssum += r[e];
#pragma unroll
  for (int e = 0; e < EDYN; ++e) {
    float v = r[e] / ssum;
    rw[t * EDYN + e] = v;
    mask[t * EDYN + e] = (v > 0.f) ? 1 : 0;
  }
}

// ---------------- capacity: parallel prefix-scan per expert ----------------
// one block per expert; 1024 threads; thread i owns tokens [4i, 4i+4)
__global__ __launch_bounds__(1024)
void capacity_kernel(int* __restrict__ mask, int* __restrict__ tok,
                     int* __restrict__ counts) {
  const int e = blockIdx.x;
  const int tid = threadIdx.x;
  const int lane = tid & 63, wave = tid >> 6;
  __shared__ int wsum[16];
  const int t0 = tid * 4;
  int bits[4]; int c = 0;
#pragma unroll
  for (int j = 0; j < 4; ++j) { bits[j] = mask[(t0 + j) * EDYN + e]; c += bits[j]; }
  int sc = c;                                  // inclusive wave scan
#pragma unroll
  for (int off = 1; off < 64; off <<= 1) {
    int v = __shfl_up(sc, off, 64);
    if (lane >= off) sc += v;
  }
  if (lane == 63) wsum[wave] = sc;
  __syncthreads();
  int wbase = 0;
  for (int w = 0; w < wave; ++w) wbase += wsum[w];
  int pos = wbase + sc - c;                    // exclusive prefix (token order)
#pragma unroll
  for (int j = 0; j < 4; ++j) {
    int keep = bits[j] && (pos < CAPE);
    if (keep) tok[e * CAPE + pos] = t0 + j;
    mask[(t0 + j) * EDYN + e] = keep;
    pos += bits[j];
  }
  int total = 0;
  for (int w = 0; w < 16; ++w) total += wsum[w];
  int cnt = total < CAPE ? total : CAPE;
  if (tid == 0) counts[e] = cnt;
  for (int r = cnt + tid; r < CAPE; r += 1024) tok[e * CAPE + r] = -1;  // pad sentinel
}

// ---------------- final gate: masked softmax over 9, global weights ----------------
__global__ __launch_bounds__(256)
void final_gate_kernel(const float* __restrict__ logits, const int* __restrict__ mask,
                       const float* __restrict__ rw, float* __restrict__ gdyn,
                       float* __restrict__ wsh) {
  int t = blockIdx.x * blockDim.x + threadIdx.x;
  if (t >= T_TOK) return;
  float vals[NEXP]; float mx = -INFINITY;
  int mk[EDYN];
#pragma unroll
  for (int e = 0; e < EDYN; ++e) {
    mk[e] = mask[t * EDYN + e];
    vals[e] = mk[e] ? logits[t * NEXP + e] : -INFINITY;
    mx = fmaxf(mx, vals[e]);
  }
  vals[EDYN] = logits[t * NEXP + EDYN];
  mx = fmaxf(mx, vals[EDYN]);
  float ex[NEXP]; float sum = 0.f;
#pragma unroll
  for (int e = 0; e < NEXP; ++e) { ex[e] = expf(vals[e] - mx); sum += ex[e]; }
  float inv = 1.f / sum;
  float sd = 0.f;
#pragma unroll
  for (int e = 0; e < EDYN; ++e) sd += ex[e] * inv;
#pragma unroll
  for (int e = 0; e < EDYN; ++e)
    gdyn[t * EDYN + e] = mk[e] ? rw[t * EDYN + e] * sd : 0.f;
  wsh[t] = ex[EDYN] * inv;
}

// ---------------- fused gate+up GEMM with SiLU epilogue ----------------
// BM=128, BN=64(x2), BK=64; 4 waves 2x2; A row-major TxK, W row-major NxK (B^T)
// nid LINEARIZED, m-fastest: m0 = (nid%MT)*128, n0 = (nid/MT)*64
template <bool GATHER>
__global__ __launch_bounds__(256)
void gemm_gateup_kernel(const unsigned short* __restrict__ xb,
                        const unsigned short* __restrict__ Wg,
                        const unsigned short* __restrict__ Wu,
                        unsigned short* __restrict__ act,
                        const int* __restrict__ toklist,
                        const int* __restrict__ counts,
                        int N, int K, int Mstride, int MT) {
  const int e = blockIdx.z;
  const int nid = blockIdx.x;
  const int m0 = (nid % MT) * 128;
  const int n0 = (nid / MT) * 64;
  if (GATHER) { if (m0 >= counts[e]) return; }

  const unsigned short* Wg_e = Wg + (size_t)e * N * K;
  const unsigned short* Wu_e = Wu + (size_t)e * N * K;
  unsigned short* act_e = act + (size_t)e * Mstride * N;
  const int* tok_e = toklist + e * CAPE;

  __shared__ __align__(16) unsigned short As[128 * 64];
  __shared__ __align__(16) unsigned short Bgs[64 * 64];
  __shared__ __align__(16) unsigned short Bus[64 * 64];

  const int tid = threadIdx.x;
  const int lane = tid & 63;
  const int wave = tid >> 6;
  const int wr = wave >> 1, wc = wave & 1;
  const int srow = tid >> 3;
  const int scol = (tid & 7) * 8;

  const unsigned short* a_src[4];
#pragma unroll
  for (int it = 0; it < 4; ++it) {
    int r = m0 + it * 32 + srow;
    int ridx = r;
    if (GATHER) { int tv = tok_e[r]; ridx = tv < 0 ? 0 : tv; }
    a_src[it] = xb + (size_t)ridx * K + scol;
  }
  const unsigned short* bg_src[2]; const unsigned short* bu_src[2];
#pragma unroll
  for (int it = 0; it < 2; ++it) {
    int r = n0 + it * 32 + srow;
    bg_src[it] = Wg_e + (size_t)r * K + scol;
    bu_src[it] = Wu_e + (size_t)r * K + scol;
  }

  f32x4 accg[4][2], accu[4][2];
#pragma unroll
  for (int i = 0; i < 4; ++i)
#pragma unroll
    for (int j = 0; j < 2; ++j) {
      f32x4 z = {0.f, 0.f, 0.f, 0.f};
      accg[i][j] = z; accu[i][j] = z;
    }

  for (int kt = 0; kt < K; kt += 64) {
#pragma unroll
    for (int it = 0; it < 4; ++it)
      gl_lds16(a_src[it] + kt, &As[it * 2048 + wave * 512]);
#pragma unroll
    for (int it = 0; it < 2; ++it) {
      gl_lds16(bg_src[it] + kt, &Bgs[it * 2048 + wave * 512]);
      gl_lds16(bu_src[it] + kt, &Bus[it * 2048 + wave * 512]);
    }
    __syncthreads();
#pragma unroll
    for (int kk = 0; kk < 2; ++kk) {
      const int ko = kk * 32 + (lane >> 4) * 8;
      bf16x8 a[4], bg[2], bu[2];
#pragma unroll
      for (int mi = 0; mi < 4; ++mi)
        a[mi] = *reinterpret_cast<const bf16x8*>(&As[(wr * 64 + mi * 16 + (lane & 15)) * 64 + ko]);
#pragma unroll
      for (int ni = 0; ni < 2; ++ni) {
        bg[ni] = *reinterpret_cast<const bf16x8*>(&Bgs[(wc * 32 + ni * 16 + (lane & 15)) * 64 + ko]);
        bu[ni] = *reinterpret_cast<const bf16x8*>(&Bus[(wc * 32 + ni * 16 + (lane & 15)) * 64 + ko]);
      }
#pragma unroll
      for (int mi = 0; mi < 4; ++mi)
#pragma unroll
        for (int ni = 0; ni < 2; ++ni) {
          accg[mi][ni] = __builtin_amdgcn_mfma_f32_16x16x32_bf16(a[mi], bg[ni], accg[mi][ni], 0, 0, 0);
          accu[mi][ni] = __builtin_amdgcn_mfma_f32_16x16x32_bf16(a[mi], bu[ni], accu[mi][ni], 0, 0, 0);
        }
    }
    __syncthreads();
  }

#pragma unroll
  for (int mi = 0; mi < 4; ++mi)
#pragma unroll
    for (int ni = 0; ni < 2; ++ni)
#pragma unroll
      for (int j = 0; j < 4; ++j) {
        int row = m0 + wr * 64 + mi * 16 + (lane >> 4) * 4 + j;
        int col = n0 + wc * 32 + ni * 16 + (lane & 15);
        float g = accg[mi][ni][j], u = accu[mi][ni][j];
        float v = (g / (1.f + __expf(-g))) * u;   // silu(g)*u
        act_e[(size_t)row * N + col] = f2bf(v);
      }
}

// ---------------- down GEMM ----------------
// BM=128, BN=128, BK=64; 4 waves 2x2, each 64x64
// nid LINEARIZED, m-fastest: m0 = (nid%MT)*128, n0 = (nid/MT)*128
template <bool DYN>
__global__ __launch_bounds__(256)
void gemm_down_kernel(const unsigned short* __restrict__ act,
                      const unsigned short* __restrict__ Wd,
                      float* __restrict__ out,
                      const int* __restrict__ toklist,
                      const int* __restrict__ counts,
                      const float* __restrict__ gdyn,
                      const float* __restrict__ wsh,
                      int N, int K, int Mstride, int MT) {
  const int e = blockIdx.z;
  const int nid = blockIdx.x;
  const int m0 = (nid % MT) * 128;
  const int n0 = (nid / MT) * 128;
  if (DYN) { if (m0 >= counts[e]) return; }

  const unsigned short* A_e = act + (size_t)e * Mstride * K;
  const unsigned short* Wd_e = Wd + (size_t)e * N * K;

  __shared__ __align__(16) unsigned short As[128 * 64];
  __shared__ __align__(16) unsigned short Bs[128 * 64];

  const int tid = threadIdx.x;
  const int lane = tid & 63;
  const int wave = tid >> 6;
  const int wr = wave >> 1, wc = wave & 1;
  const int srow = tid >> 3;
  const int scol = (tid & 7) * 8;

  const unsigned short* a_src[4]; const unsigned short* b_src[4];
#pragma unroll
  for (int it = 0; it < 4; ++it) {
    a_src[it] = A_e + (size_t)(m0 + it * 32 + srow) * K + scol;
    b_src[it] = Wd_e + (size_t)(n0 + it * 32 + srow) * K + scol;
  }

  f32x4 acc[4][4];
#pragma unroll
  for (int i = 0; i < 4; ++i)
#pragma unroll
    for (int j = 0; j < 4; ++j) { f32x4 z = {0.f, 0.f, 0.f, 0.f}; acc[i][j] = z; }

  for (int kt = 0; kt < K; kt += 64) {
#pragma unroll
    for (int it = 0; it < 4; ++it) {
      gl_lds16(a_src[it] + kt, &As[it * 2048 + wave * 512]);
      gl_lds16(b_src[it] + kt, &Bs[it * 2048 + wave * 512]);
    }
    __syncthreads();
#pragma unroll
    for (int kk = 0; kk < 2; ++kk) {
      const int ko = kk * 32 + (lane >> 4) * 8;
      bf16x8 a[4], b[4];
#pragma unroll
      for (int mi = 0; mi < 4; ++mi)
        a[mi] = *reinterpret_cast<const bf16x8*>(&As[(wr * 64 + mi * 16 + (lane & 15)) * 64 + ko]);
#pragma unroll
      for (int ni = 0; ni < 4; ++ni)
        b[ni] = *reinterpret_cast<const bf16x8*>(&Bs[(wc * 64 + ni * 16 + (lane & 15)) * 64 + ko]);
#pragma unroll
      for (int mi = 0; mi < 4; ++mi)
#pragma unroll
        for (int ni = 0; ni < 4; ++ni)
          acc[mi][ni] = __builtin_amdgcn_mfma_f32_16x16x32_bf16(a[mi], b[ni], acc[mi][ni], 0, 0, 0);
    }
    __syncthreads();
  }

#pragma unroll
  for (int mi = 0; mi < 4; ++mi)
#pragma unroll
    for (int ni = 0; ni < 4; ++ni)
#pragma unroll
      for (int j = 0; j < 4; ++j) {
        int row = m0 + wr * 64 + mi * 16 + (lane >> 4) * 4 + j;
        int col = n0 + wc * 64 + ni * 16 + (lane & 15);
        float v = acc[mi][ni][j];
        if (DYN) {
          int t = toklist[e * CAPE + row];
          if (t >= 0)
            atomicAdd(&out[(size_t)t * HDIM + col], gdyn[t * EDYN + e] * v);
        } else {
          out[(size_t)row * HDIM + col] = wsh[row] * v;  // runs before dyn adds
        }
      }
}

// ---------------- host ----------------
extern "C" void kernel_launch(void* const* d_in, const int* in_sizes, int n_in,
                              void* d_out, int out_size, void* d_ws, size_t ws_size,
                              hipStream_t stream) {
  const float* x   = (const float*)d_in[0];
  const float* gw  = (const float*)d_in[1];
  const float* wdg = (const float*)d_in[2];
  const float* wdu = (const float*)d_in[3];
  const float* wdd = (const float*)d_in[4];
  const float* wsg = (const float*)d_in[5];
  const float* wsu = (const float*)d_in[6];
  const float* wsd = (const float*)d_in[7];
  float* out = (float*)d_out;

  char* p = (char*)d_ws;
  auto alloc = [&](size_t bytes) {
    char* r = p; p += (bytes + 255) & ~(size_t)255; return r;
  };
  unsigned short* xb    = (unsigned short*)alloc((size_t)T_TOK * HDIM * 2);
  unsigned short* wdgb  = (unsigned short*)alloc((size_t)EDYN * IDYN_ * HDIM * 2);
  unsigned short* wdub  = (unsigned short*)alloc((size_t)EDYN * IDYN_ * HDIM * 2);
  unsigned short* wddb  = (unsigned short*)alloc((size_t)EDYN * HDIM * IDYN_ * 2);
  unsigned short* wsgb  = (unsigned short*)alloc((size_t)IFIX_ * HDIM * 2);
  unsigned short* wsub  = (unsigned short*)alloc((size_t)IFIX_ * HDIM * 2);
  unsigned short* wsdb  = (unsigned short*)alloc((size_t)HDIM * IFIX_ * 2);
  unsigned short* actsh = (unsigned short*)alloc((size_t)T_TOK * IFIX_ * 2);
  unsigned short* actdy = (unsigned short*)alloc((size_t)EDYN * CAPE * IDYN_ * 2);
  float* logits = (float*)alloc((size_t)T_TOK * NEXP * 4);
  float* rw     = (float*)alloc((size_t)T_TOK * EDYN * 4);
  int*   mask   = (int*)alloc((size_t)T_TOK * EDYN * 4);
  float* gdyn   = (float*)alloc((size_t)T_TOK * EDYN * 4);
  float* wshv   = (float*)alloc((size_t)T_TOK * 4);
  int*   counts = (int*)alloc(256);
  int*   tok    = (int*)alloc((size_t)EDYN * CAPE * 4);

  cvt_all_kernel<<<dim3(2048), dim3(256), 0, stream>>>(
      (const float4*)wdg, (const float4*)wdu, (const float4*)wdd,
      (const float4*)wsg, (const float4*)wsu, (const float4*)wsd,
      (ushort4*)wdgb, (ushort4*)wdub, (ushort4*)wddb,
      (ushort4*)wsgb, (ushort4*)wsub, (ushort4*)wsdb);

  logits_routing_kernel<<<dim3(T_TOK / 4), dim3(256), 0, stream>>>(x, gw, xb, logits, rw, mask);
  capacity_kernel<<<dim3(EDYN), dim3(1024), 0, stream>>>(mask, tok, counts);
  final_gate_kernel<<<dim3(T_TOK / 256), dim3(256), 0, stream>>>(logits, mask, rw, gdyn, wshv);

  // shared expert (writes every out element) ...
  gemm_gateup_kernel<false><<<dim3((T_TOK / 128) * (IFIX_ / 64), 1, 1), dim3(256), 0, stream>>>(
      xb, wsgb, wsub, actsh, tok, counts, IFIX_, HDIM, T_TOK, T_TOK / 128);
  gemm_down_kernel<false><<<dim3((T_TOK / 128) * (HDIM / 128), 1, 1), dim3(256), 0, stream>>>(
      actsh, wsdb, out, tok, counts, gdyn, wshv, HDIM, IFIX_, T_TOK, T_TOK / 128);
  // ... then dyn experts accumulate on top (stream-ordered after shared store)
  gemm_gateup_kernel<true><<<dim3((CAPE / 128) * (IDYN_ / 64), 1, EDYN), dim3(256), 0, stream>>>(
      xb, wdgb, wdub, actdy, tok, counts, IDYN_, HDIM, CAPE, CAPE / 128);
  gemm_down_kernel<true><<<dim3((CAPE / 128) * (HDIM / 128), 1, EDYN), dim3(256), 0, stream>>>(
      actdy, wddb, out, tok, counts, gdyn, wshv, HDIM, IDYN_, CAPE, CAPE / 128);
}

// Round 6
// 317.630 us; speedup vs baseline: 1.1274x; 1.0535x over previous
//
#include <hip/hip_runtime.h>
#include <cstdint>

typedef __attribute__((ext_vector_type(8))) __bf16 bf16x8;
typedef __attribute__((ext_vector_type(4))) float f32x4;

static constexpr int T_TOK = 4096;   // B*S
static constexpr int HDIM  = 1024;
static constexpr int NEXP  = 9;      // E_DYN + E_FIX
static constexpr int EDYN  = 8;
static constexpr int IDYN_ = 512;
static constexpr int IFIX_ = 2048;
static constexpr int CAPE  = 640;    // ceil(T/E_DYN*1.25) = 640 = 5*128

__device__ __forceinline__ unsigned short f2bf(float f) {
  unsigned u = __float_as_uint(f);
  u += 0x7fffu + ((u >> 16) & 1u);   // RNE
  return (unsigned short)(u >> 16);
}

__device__ __forceinline__ void gl_lds16(const void* g, void* l) {
  __builtin_amdgcn_global_load_lds((const __attribute__((address_space(1))) void*)g,
                                   (__attribute__((address_space(3))) void*)l,
                                   16, 0, 0);
}

// ---------------- fused fp32 -> bf16 conversion (6 weight tensors) ----------------
static constexpr int D0 = 1048576;            // dyn_gate (8*512*1024/4)
static constexpr int D1 = D0 + 1048576;       // dyn_up
static constexpr int D2 = D1 + 1048576;       // dyn_down
static constexpr int D3 = D2 + 524288;        // sh_gate  (2048*1024/4)
static constexpr int D4 = D3 + 524288;        // sh_up
static constexpr int D5 = D4 + 524288;        // sh_down
__global__ void cvt_all_kernel(const float4* __restrict__ s1,
                               const float4* __restrict__ s2, const float4* __restrict__ s3,
                               const float4* __restrict__ s4, const float4* __restrict__ s5,
                               const float4* __restrict__ s6,
                               ushort4* __restrict__ d1,
                               ushort4* __restrict__ d2, ushort4* __restrict__ d3,
                               ushort4* __restrict__ d4, ushort4* __restrict__ d5,
                               ushort4* __restrict__ d6) {
  int stride = gridDim.x * blockDim.x;
  for (int i = blockIdx.x * blockDim.x + threadIdx.x; i < D5; i += stride) {
    const float4* s; ushort4* d; int off;
    if      (i < D0) { s = s1; d = d1; off = i; }
    else if (i < D1) { s = s2; d = d2; off = i - D0; }
    else if (i < D2) { s = s3; d = d3; off = i - D1; }
    else if (i < D3) { s = s4; d = d4; off = i - D2; }
    else if (i < D4) { s = s5; d = d5; off = i - D3; }
    else             { s = s6; d = d6; off = i - D4; }
    float4 f = s[off];
    d[off] = make_ushort4(f2bf(f.x), f2bf(f.y), f2bf(f.z), f2bf(f.w));
  }
}

// ---------------- gating logits + routing + x->bf16 (fused) ----------------
__global__ __launch_bounds__(256)
void logits_routing_kernel(const float* __restrict__ x, const float* __restrict__ gw,
                           unsigned short* __restrict__ xb,
                           float* __restrict__ logits, float* __restrict__ rw,
                           int* __restrict__ mask) {
  int wave = threadIdx.x >> 6, lane = threadIdx.x & 63;
  int t = blockIdx.x * 4 + wave;
  if (t >= T_TOK) return;
  const float* xr = x + (size_t)t * HDIM;
  float acc[NEXP];
#pragma unroll
  for (int e = 0; e < NEXP; ++e) acc[e] = 0.f;
#pragma unroll
  for (int half = 0; half < 2; ++half) {
    const int h0 = half * 512 + lane * 8;
    float4 a = *(const float4*)(xr + h0);
    float4 b = *(const float4*)(xr + h0 + 4);
    float v[8] = {a.x, a.y, a.z, a.w, b.x, b.y, b.z, b.w};
    union { unsigned short us[8]; uint4 u4; } pk;
#pragma unroll
    for (int j = 0; j < 8; ++j) pk.us[j] = f2bf(v[j]);
    *(uint4*)(xb + (size_t)t * HDIM + h0) = pk.u4;   // coalesced 16B/lane
#pragma unroll
    for (int e = 0; e < NEXP; ++e) {
      float s = 0.f;
#pragma unroll
      for (int j = 0; j < 8; ++j) s += v[j] * gw[e * HDIM + h0 + j];
      acc[e] += s;
    }
  }
#pragma unroll
  for (int e = 0; e < NEXP; ++e) {
    float v = acc[e];
#pragma unroll
    for (int off = 32; off > 0; off >>= 1) v += __shfl_down(v, off, 64);
    acc[e] = v;
  }
  if (lane != 0) return;
  float s[EDYN];
#pragma unroll
  for (int e = 0; e < NEXP; ++e) logits[t * NEXP + e] = acc[e];
#pragma unroll
  for (int e = 0; e < EDYN; ++e) s[e] = acc[e];

  float m = s[0];
#pragma unroll
  for (int e = 1; e < EDYN; ++e) m = fmaxf(m, s[e]);
  float p[EDYN]; float psum = 0.f;
#pragma unroll
  for (int e = 0; e < EDYN; ++e) { p[e] = expf(s[e] - m); psum += p[e]; }
#pragma unroll
  for (int e = 0; e < EDYN; ++e) p[e] /= psum;
  float sp[EDYN];
#pragma unroll
  for (int e = 0; e < EDYN; ++e) sp[e] = p[e];
  for (int i = 1; i < EDYN; ++i) {            // insertion sort descending
    float key = sp[i]; int j = i - 1;
    while (j >= 0 && sp[j] < key) { sp[j + 1] = sp[j]; --j; }
    sp[j + 1] = key;
  }
  float c = 0.f; int cnt = 0;
#pragma unroll
  for (int e = 0; e < EDYN; ++e) { c += sp[e]; cnt += (c < 0.75f) ? 1 : 0; }
  int dyn_k = cnt + 1; if (dyn_k > 4) dyn_k = 4;

  float ms[EDYN];
#pragma unroll
  for (int e = 0; e < EDYN; ++e) ms[e] = s[e];
  float mult[4]; int sel[4];
  for (int k = 0; k < 4; ++k) {
    float thr = ms[0]; int am = 0;
#pragma unroll
    for (int e = 1; e < EDYN; ++e) if (ms[e] > thr) { thr = ms[e]; am = e; }
    float vals[EDYN]; float mx = -INFINITY;
#pragma unroll
    for (int e = 0; e < EDYN; ++e) {
      float factor = fmaxf(fabsf(s[e]), fabsf(thr));
      float ratio = (thr - s[e]) / factor;          // NaN (0/0) compares false
      float v = (ratio > 0.2f) ? -INFINITY : ms[e];
      vals[e] = v; mx = fmaxf(mx, v);
    }
    float sum = 0.f;
#pragma unroll
    for (int e = 0; e < EDYN; ++e) sum += expf(vals[e] - mx);
    mult[k] = expf(vals[am] - mx) / sum;
    sel[k] = am;
    ms[am] = -INFINITY;
  }
  float r[EDYN];
#pragma unroll
  for (int e = 0; e < EDYN; ++e) r[e] = 0.f;
  for (int k = 0; k < 4; ++k) if (k < dyn_k) r[sel[k]] += mult[k];
  float ssum = 0.f;
#pragma unroll
  for (int e = 0; e < EDYN; ++e) ssum += r[e];
#pragma unroll
  for (int e = 0; e < EDYN; ++e) {
    float v = r[e] / ssum;
    rw[t * EDYN + e] = v;
    mask[t * EDYN + e] = (v > 0.f) ? 1 : 0;
  }
}

// ---------------- capacity: parallel prefix-scan per expert ----------------
__global__ __launch_bounds__(1024)
void capacity_kernel(int* __restrict__ mask, int* __restrict__ tok,
                     int* __restrict__ counts) {
  const int e = blockIdx.x;
  const int tid = threadIdx.x;
  const int lane = tid & 63, wave = tid >> 6;
  __shared__ int wsum[16];
  const int t0 = tid * 4;
  int bits[4]; int c = 0;
#pragma unroll
  for (int j = 0; j < 4; ++j) { bits[j] = mask[(t0 + j) * EDYN + e]; c += bits[j]; }
  int sc = c;                                  // inclusive wave scan
#pragma unroll
  for (int off = 1; off < 64; off <<= 1) {
    int v = __shfl_up(sc, off, 64);
    if (lane >= off) sc += v;
  }
  if (lane == 63) wsum[wave] = sc;
  __syncthreads();
  int wbase = 0;
  for (int w = 0; w < wave; ++w) wbase += wsum[w];
  int pos = wbase + sc - c;                    // exclusive prefix (token order)
#pragma unroll
  for (int j = 0; j < 4; ++j) {
    int keep = bits[j] && (pos < CAPE);
    if (keep) tok[e * CAPE + pos] = t0 + j;
    mask[(t0 + j) * EDYN + e] = keep;
    pos += bits[j];
  }
  int total = 0;
  for (int w = 0; w < 16; ++w) total += wsum[w];
  int cnt = total < CAPE ? total : CAPE;
  if (tid == 0) counts[e] = cnt;
  for (int r = cnt + tid; r < CAPE; r += 1024) tok[e * CAPE + r] = -1;  // pad sentinel
}

// ---------------- final gate ----------------
__global__ __launch_bounds__(256)
void final_gate_kernel(const float* __restrict__ logits, const int* __restrict__ mask,
                       const float* __restrict__ rw, float* __restrict__ gdyn,
                       float* __restrict__ wsh) {
  int t = blockIdx.x * blockDim.x + threadIdx.x;
  if (t >= T_TOK) return;
  float vals[NEXP]; float mx = -INFINITY;
  int mk[EDYN];
#pragma unroll
  for (int e = 0; e < EDYN; ++e) {
    mk[e] = mask[t * EDYN + e];
    vals[e] = mk[e] ? logits[t * NEXP + e] : -INFINITY;
    mx = fmaxf(mx, vals[e]);
  }
  vals[EDYN] = logits[t * NEXP + EDYN];
  mx = fmaxf(mx, vals[EDYN]);
  float ex[NEXP]; float sum = 0.f;
#pragma unroll
  for (int e = 0; e < NEXP; ++e) { ex[e] = expf(vals[e] - mx); sum += ex[e]; }
  float inv = 1.f / sum;
  float sd = 0.f;
#pragma unroll
  for (int e = 0; e < EDYN; ++e) sd += ex[e] * inv;
#pragma unroll
  for (int e = 0; e < EDYN; ++e)
    gdyn[t * EDYN + e] = mk[e] ? rw[t * EDYN + e] * sd : 0.f;
  wsh[t] = ex[EDYN] * inv;
}

// ---------------- shared gate+up: 256x(128+128) tile, 4-phase counted-vmcnt ----------------
// 8 waves (2M x 4N), 512 thr. LDS/buf: A0@0,A1@16K,Bg@32K,Bu@48K; dbuf stride 64K.
// K-tile stored [row][ks(2)][32 elems], 64B rows, swizzle byte5 ^= row.bit3 (st_16x32).
// Stage: linear gl_lds dest + inverse-swizzled global src; read with same XOR.
// Waits: vmcnt(4)@ph2, vmcnt(2)@ph4 (2 loads/half-tile; derivation in journal).
__global__ __launch_bounds__(512, 2)
void gemm_gateup_8ph(const unsigned short* __restrict__ xb,
                     const unsigned short* __restrict__ Wg,
                     const unsigned short* __restrict__ Wu,
                     unsigned short* __restrict__ act) {
  extern __shared__ char lds[];
  constexpr int NT = HDIM / 64;          // 16 K-tiles
  const int tid  = threadIdx.x;
  const int lane = tid & 63;
  const int wid  = tid >> 6;
  const int wrh  = wid >> 2;             // 0..1  M-half (128 rows each)
  const int wc   = wid & 3;              // 0..3  N-quarter (32 cols each)
  const int m0 = (blockIdx.x & 15) * 256;
  const int n0 = (blockIdx.x >> 4) * 128;

  // ---- staging lane geometry (per half-tile: 128 rows x 128B, 2 rounds ks=0/1) ----
  const int srow = wid * 16 + (lane >> 2);               // 0..127
  const int sb9  = (lane >> 5) & 1;                      // row bit3
  const int scl  = ((lane & 3) << 4) ^ (sb9 << 5);       // inverse-swizzled col byte
  const char* sA0 = (const char*)xb + (size_t)(m0 + srow) * 2048 + scl;
  const char* sA1 = sA0 + (size_t)128 * 2048;
  const char* sBg = (const char*)Wg + (size_t)(n0 + srow) * 2048 + scl;
  const char* sBu = (const char*)Wu + (size_t)(n0 + srow) * 2048 + scl;
  const int ldsW = wid * 1024;                           // wave chunk in half-tile

  // ---- read lane geometry ----
  const int rl  = lane & 15;
  const int swz = ((lane >> 4) << 4) ^ ((rl & 8) << 2);  // kc ^ bankfix
  const int aRd = wrh * 16384 + rl * 64 + swz;
  const int bRd = wc * 2048 + rl * 64 + swz;

  f32x4 accg[8][2], accu[8][2];
#pragma unroll
  for (int i = 0; i < 8; ++i)
#pragma unroll
    for (int j = 0; j < 2; ++j) {
      f32x4 z = {0.f, 0.f, 0.f, 0.f};
      accg[i][j] = z; accu[i][j] = z;
    }
  bf16x8 aF[2][4][2];   // [h][rf][ks]
  bf16x8 bF[2][2];      // [cf][ks]

#define STAGE8(srcp, regoff)                                               \
  if (ktN < NT) {                                                          \
    gl_lds16((srcp) + (size_t)ktN * 128,       lds + nxt * 65536 + (regoff) + ldsW);          \
    gl_lds16((srcp) + (size_t)ktN * 128 + 64,  lds + nxt * 65536 + (regoff) + 8192 + ldsW);   \
  }
#define LOAD_A8(h)                                                         \
  _Pragma("unroll") for (int rf = 0; rf < 4; ++rf)                         \
  _Pragma("unroll") for (int ks = 0; ks < 2; ++ks)                         \
    aF[h][rf][ks] = *reinterpret_cast<const bf16x8*>(                      \
      lds + cur * 65536 + aRd + ks * 8192 + (h) * 4096 + rf * 1024);
#define LOAD_B8(off)                                                       \
  _Pragma("unroll") for (int cf = 0; cf < 2; ++cf)                         \
  _Pragma("unroll") for (int ks = 0; ks < 2; ++ks)                         \
    bF[cf][ks] = *reinterpret_cast<const bf16x8*>(                         \
      lds + cur * 65536 + (off) + bRd + ks * 8192 + cf * 1024);
#define MFMA_PH8(h, ACC)                                                   \
  __builtin_amdgcn_s_setprio(1);                                           \
  _Pragma("unroll") for (int rf = 0; rf < 4; ++rf)                         \
  _Pragma("unroll") for (int cf = 0; cf < 2; ++cf)                         \
  _Pragma("unroll") for (int ks = 0; ks < 2; ++ks)                         \
    ACC[(h) * 4 + rf][cf] = __builtin_amdgcn_mfma_f32_16x16x32_bf16(       \
        aF[h][rf][ks], bF[cf][ks], ACC[(h) * 4 + rf][cf], 0, 0, 0);        \
  __builtin_amdgcn_s_setprio(0);
#define BAR8() __builtin_amdgcn_sched_barrier(0);                          \
               __builtin_amdgcn_s_barrier();                               \
               __builtin_amdgcn_sched_barrier(0);

  // prologue: stage tile 0 into buf 0, drain once
  {
    const int ktN = 0, nxt = 0;
    STAGE8(sA0, 0) STAGE8(sA1, 16384) STAGE8(sBg, 32768) STAGE8(sBu, 49152)
  }
  asm volatile("s_waitcnt vmcnt(0)" ::: "memory");
  BAR8()

  for (int j = 0; j < NT; ++j) {
    const int cur = j & 1, nxt = cur ^ 1, ktN = j + 1;
    // ph1: (h0, gate)
    STAGE8(sA0, 0)
    LOAD_A8(0)
    LOAD_B8(32768)
    MFMA_PH8(0, accg)
    BAR8()
    // ph2: (h1, gate)
    STAGE8(sA1, 16384)
    LOAD_A8(1)
    MFMA_PH8(1, accg)
    asm volatile("s_waitcnt vmcnt(4)" ::: "memory");   // prev Bu landed
    BAR8()
    // ph3: (h0, up)
    STAGE8(sBg, 32768)
    LOAD_B8(49152)
    MFMA_PH8(0, accu)
    BAR8()
    // ph4: (h1, up)
    STAGE8(sBu, 49152)
    MFMA_PH8(1, accu)
    asm volatile("s_waitcnt vmcnt(2)" ::: "memory");   // next A0/A1/Bg landed
    BAR8()
  }

#pragma unroll
  for (int rf = 0; rf < 8; ++rf)
#pragma unroll
    for (int cf = 0; cf < 2; ++cf)
#pragma unroll
      for (int jj = 0; jj < 4; ++jj) {
        int row = m0 + wrh * 128 + (rf >> 2) * 64 + (rf & 3) * 16 + ((lane >> 4) << 2) + jj;
        int col = n0 + wc * 32 + cf * 16 + (lane & 15);
        float g = accg[rf][cf][jj], u = accu[rf][cf][jj];
        float v = (g / (1.f + __expf(-g))) * u;   // silu(g)*u
        act[(size_t)row * IFIX_ + col] = f2bf(v);
      }
#undef STAGE8
#undef LOAD_A8
#undef LOAD_B8
#undef MFMA_PH8
#undef BAR8
}

// ---------------- dyn gate+up GEMM (gathered), 2-phase 128x64x2 ----------------
__global__ __launch_bounds__(256)
void gemm_gateup_dyn(const unsigned short* __restrict__ xb,
                     const unsigned short* __restrict__ Wg,
                     const unsigned short* __restrict__ Wu,
                     unsigned short* __restrict__ act,
                     const int* __restrict__ toklist,
                     const int* __restrict__ counts,
                     int N, int K, int Mstride, int MT) {
  const int e = blockIdx.z;
  const int nid = blockIdx.x;
  const int m0 = (nid % MT) * 128;
  const int n0 = (nid / MT) * 64;
  if (m0 >= counts[e]) return;

  const unsigned short* Wg_e = Wg + (size_t)e * N * K;
  const unsigned short* Wu_e = Wu + (size_t)e * N * K;
  unsigned short* act_e = act + (size_t)e * Mstride * N;
  const int* tok_e = toklist + e * CAPE;

  __shared__ __align__(16) unsigned short As[128 * 64];
  __shared__ __align__(16) unsigned short Bgs[64 * 64];
  __shared__ __align__(16) unsigned short Bus[64 * 64];

  const int tid = threadIdx.x;
  const int lane = tid & 63;
  const int wave = tid >> 6;
  const int wr = wave >> 1, wc = wave & 1;
  const int srow = tid >> 3;
  const int scol = (tid & 7) * 8;

  const unsigned short* a_src[4];
#pragma unroll
  for (int it = 0; it < 4; ++it) {
    int r = m0 + it * 32 + srow;
    int tv = tok_e[r];
    a_src[it] = xb + (size_t)(tv < 0 ? 0 : tv) * K + scol;
  }
  const unsigned short* bg_src[2]; const unsigned short* bu_src[2];
#pragma unroll
  for (int it = 0; it < 2; ++it) {
    int r = n0 + it * 32 + srow;
    bg_src[it] = Wg_e + (size_t)r * K + scol;
    bu_src[it] = Wu_e + (size_t)r * K + scol;
  }

  f32x4 accg[4][2], accu[4][2];
#pragma unroll
  for (int i = 0; i < 4; ++i)
#pragma unroll
    for (int j = 0; j < 2; ++j) {
      f32x4 z = {0.f, 0.f, 0.f, 0.f};
      accg[i][j] = z; accu[i][j] = z;
    }

  for (int kt = 0; kt < K; kt += 64) {
#pragma unroll
    for (int it = 0; it < 4; ++it)
      gl_lds16(a_src[it] + kt, &As[it * 2048 + wave * 512]);
#pragma unroll
    for (int it = 0; it < 2; ++it) {
      gl_lds16(bg_src[it] + kt, &Bgs[it * 2048 + wave * 512]);
      gl_lds16(bu_src[it] + kt, &Bus[it * 2048 + wave * 512]);
    }
    __syncthreads();
#pragma unroll
    for (int kk = 0; kk < 2; ++kk) {
      const int ko = kk * 32 + (lane >> 4) * 8;
      bf16x8 a[4], bg[2], bu[2];
#pragma unroll
      for (int mi = 0; mi < 4; ++mi)
        a[mi] = *reinterpret_cast<const bf16x8*>(&As[(wr * 64 + mi * 16 + (lane & 15)) * 64 + ko]);
#pragma unroll
      for (int ni = 0; ni < 2; ++ni) {
        bg[ni] = *reinterpret_cast<const bf16x8*>(&Bgs[(wc * 32 + ni * 16 + (lane & 15)) * 64 + ko]);
        bu[ni] = *reinterpret_cast<const bf16x8*>(&Bus[(wc * 32 + ni * 16 + (lane & 15)) * 64 + ko]);
      }
#pragma unroll
      for (int mi = 0; mi < 4; ++mi)
#pragma unroll
        for (int ni = 0; ni < 2; ++ni) {
          accg[mi][ni] = __builtin_amdgcn_mfma_f32_16x16x32_bf16(a[mi], bg[ni], accg[mi][ni], 0, 0, 0);
          accu[mi][ni] = __builtin_amdgcn_mfma_f32_16x16x32_bf16(a[mi], bu[ni], accu[mi][ni], 0, 0, 0);
        }
    }
    __syncthreads();
  }

#pragma unroll
  for (int mi = 0; mi < 4; ++mi)
#pragma unroll
    for (int ni = 0; ni < 2; ++ni)
#pragma unroll
      for (int j = 0; j < 4; ++j) {
        int row = m0 + wr * 64 + mi * 16 + (lane >> 4) * 4 + j;
        int col = n0 + wc * 32 + ni * 16 + (lane & 15);
        float g = accg[mi][ni][j], u = accu[mi][ni][j];
        float v = (g / (1.f + __expf(-g))) * u;   // silu(g)*u
        act_e[(size_t)row * N + col] = f2bf(v);
      }
}

// ---------------- down GEMM (unchanged 2-phase) ----------------
template <bool DYN>
__global__ __launch_bounds__(256)
void gemm_down_kernel(const unsigned short* __restrict__ act,
                      const unsigned short* __restrict__ Wd,
                      float* __restrict__ out,
                      const int* __restrict__ toklist,
                      const int* __restrict__ counts,
                      const float* __restrict__ gdyn,
                      const float* __restrict__ wsh,
                      int N, int K, int Mstride, int MT) {
  const int e = blockIdx.z;
  const int nid = blockIdx.x;
  const int m0 = (nid % MT) * 128;
  const int n0 = (nid / MT) * 128;
  if (DYN) { if (m0 >= counts[e]) return; }

  const unsigned short* A_e = act + (size_t)e * Mstride * K;
  const unsigned short* Wd_e = Wd + (size_t)e * N * K;

  __shared__ __align__(16) unsigned short As[128 * 64];
  __shared__ __align__(16) unsigned short Bs[128 * 64];

  const int tid = threadIdx.x;
  const int lane = tid & 63;
  const int wave = tid >> 6;
  const int wr = wave >> 1, wc = wave & 1;
  const int srow = tid >> 3;
  const int scol = (tid & 7) * 8;

  const unsigned short* a_src[4]; const unsigned short* b_src[4];
#pragma unroll
  for (int it = 0; it < 4; ++it) {
    a_src[it] = A_e + (size_t)(m0 + it * 32 + srow) * K + scol;
    b_src[it] = Wd_e + (size_t)(n0 + it * 32 + srow) * K + scol;
  }

  f32x4 acc[4][4];
#pragma unroll
  for (int i = 0; i < 4; ++i)
#pragma unroll
    for (int j = 0; j < 4; ++j) { f32x4 z = {0.f, 0.f, 0.f, 0.f}; acc[i][j] = z; }

  for (int kt = 0; kt < K; kt += 64) {
#pragma unroll
    for (int it = 0; it < 4; ++it) {
      gl_lds16(a_src[it] + kt, &As[it * 2048 + wave * 512]);
      gl_lds16(b_src[it] + kt, &Bs[it * 2048 + wave * 512]);
    }
    __syncthreads();
#pragma unroll
    for (int kk = 0; kk < 2; ++kk) {
      const int ko = kk * 32 + (lane >> 4) * 8;
      bf16x8 a[4], b[4];
#pragma unroll
      for (int mi = 0; mi < 4; ++mi)
        a[mi] = *reinterpret_cast<const bf16x8*>(&As[(wr * 64 + mi * 16 + (lane & 15)) * 64 + ko]);
#pragma unroll
      for (int ni = 0; ni < 4; ++ni)
        b[ni] = *reinterpret_cast<const bf16x8*>(&Bs[(wc * 64 + ni * 16 + (lane & 15)) * 64 + ko]);
#pragma unroll
      for (int mi = 0; mi < 4; ++mi)
#pragma unroll
        for (int ni = 0; ni < 4; ++ni)
          acc[mi][ni] = __builtin_amdgcn_mfma_f32_16x16x32_bf16(a[mi], b[ni], acc[mi][ni], 0, 0, 0);
    }
    __syncthreads();
  }

#pragma unroll
  for (int mi = 0; mi < 4; ++mi)
#pragma unroll
    for (int ni = 0; ni < 4; ++ni)
#pragma unroll
      for (int j = 0; j < 4; ++j) {
        int row = m0 + wr * 64 + mi * 16 + (lane >> 4) * 4 + j;
        int col = n0 + wc * 64 + ni * 16 + (lane & 15);
        float v = acc[mi][ni][j];
        if (DYN) {
          int t = toklist[e * CAPE + row];
          if (t >= 0)
            atomicAdd(&out[(size_t)t * HDIM + col], gdyn[t * EDYN + e] * v);
        } else {
          out[(size_t)row * HDIM + col] = wsh[row] * v;  // runs before dyn adds
        }
      }
}

// ---------------- host ----------------
extern "C" void kernel_launch(void* const* d_in, const int* in_sizes, int n_in,
                              void* d_out, int out_size, void* d_ws, size_t ws_size,
                              hipStream_t stream) {
  const float* x   = (const float*)d_in[0];
  const float* gw  = (const float*)d_in[1];
  const float* wdg = (const float*)d_in[2];
  const float* wdu = (const float*)d_in[3];
  const float* wdd = (const float*)d_in[4];
  const float* wsg = (const float*)d_in[5];
  const float* wsu = (const float*)d_in[6];
  const float* wsd = (const float*)d_in[7];
  float* out = (float*)d_out;

  char* p = (char*)d_ws;
  auto alloc = [&](size_t bytes) {
    char* r = p; p += (bytes + 255) & ~(size_t)255; return r;
  };
  unsigned short* xb    = (unsigned short*)alloc((size_t)T_TOK * HDIM * 2);
  unsigned short* wdgb  = (unsigned short*)alloc((size_t)EDYN * IDYN_ * HDIM * 2);
  unsigned short* wdub  = (unsigned short*)alloc((size_t)EDYN * IDYN_ * HDIM * 2);
  unsigned short* wddb  = (unsigned short*)alloc((size_t)EDYN * HDIM * IDYN_ * 2);
  unsigned short* wsgb  = (unsigned short*)alloc((size_t)IFIX_ * HDIM * 2);
  unsigned short* wsub  = (unsigned short*)alloc((size_t)IFIX_ * HDIM * 2);
  unsigned short* wsdb  = (unsigned short*)alloc((size_t)HDIM * IFIX_ * 2);
  unsigned short* actsh = (unsigned short*)alloc((size_t)T_TOK * IFIX_ * 2);
  unsigned short* actdy = (unsigned short*)alloc((size_t)EDYN * CAPE * IDYN_ * 2);
  float* logits = (float*)alloc((size_t)T_TOK * NEXP * 4);
  float* rw     = (float*)alloc((size_t)T_TOK * EDYN * 4);
  int*   mask   = (int*)alloc((size_t)T_TOK * EDYN * 4);
  float* gdyn   = (float*)alloc((size_t)T_TOK * EDYN * 4);
  float* wshv   = (float*)alloc((size_t)T_TOK * 4);
  int*   counts = (int*)alloc(256);
  int*   tok    = (int*)alloc((size_t)EDYN * CAPE * 4);

  cvt_all_kernel<<<dim3(2048), dim3(256), 0, stream>>>(
      (const float4*)wdg, (const float4*)wdu, (const float4*)wdd,
      (const float4*)wsg, (const float4*)wsu, (const float4*)wsd,
      (ushort4*)wdgb, (ushort4*)wdub, (ushort4*)wddb,
      (ushort4*)wsgb, (ushort4*)wsub, (ushort4*)wsdb);

  logits_routing_kernel<<<dim3(T_TOK / 4), dim3(256), 0, stream>>>(x, gw, xb, logits, rw, mask);
  capacity_kernel<<<dim3(EDYN), dim3(1024), 0, stream>>>(mask, tok, counts);
  final_gate_kernel<<<dim3(T_TOK / 256), dim3(256), 0, stream>>>(logits, mask, rw, gdyn, wshv);

  // shared expert: 8-phase 256x(128+128) gate+up, then down (writes every out element)
  gemm_gateup_8ph<<<dim3(256), dim3(512), 131072, stream>>>(xb, wsgb, wsub, actsh);
  gemm_down_kernel<false><<<dim3((T_TOK / 128) * (HDIM / 128), 1, 1), dim3(256), 0, stream>>>(
      actsh, wsdb, out, tok, counts, gdyn, wshv, HDIM, IFIX_, T_TOK, T_TOK / 128);
  // dyn experts accumulate on top (stream-ordered after shared store)
  gemm_gateup_dyn<<<dim3((CAPE / 128) * (IDYN_ / 64), 1, EDYN), dim3(256), 0, stream>>>(
      xb, wdgb, wdub, actdy, tok, counts, IDYN_, HDIM, CAPE, CAPE / 128);
  gemm_down_kernel<true><<<dim3((CAPE / 128) * (HDIM / 128), 1, EDYN), dim3(256), 0, stream>>>(
      actdy, wddb, out, tok, counts, gdyn, wshv, HDIM, IDYN_, CAPE, CAPE / 128);
}

// Round 7
// 307.154 us; speedup vs baseline: 1.1658x; 1.0341x over previous
//
#include <hip/hip_runtime.h>
#include <cstdint>

typedef __attribute__((ext_vector_type(8))) __bf16 bf16x8;
typedef __attribute__((ext_vector_type(4))) float f32x4;

static constexpr int T_TOK = 4096;   // B*S
static constexpr int HDIM  = 1024;
static constexpr int NEXP  = 9;      // E_DYN + E_FIX
static constexpr int EDYN  = 8;
static constexpr int IDYN_ = 512;
static constexpr int IFIX_ = 2048;
static constexpr int CAPE  = 640;    // ceil(T/E_DYN*1.25) = 640 = 5*128

__device__ __forceinline__ unsigned short f2bf(float f) {
  unsigned u = __float_as_uint(f);
  u += 0x7fffu + ((u >> 16) & 1u);   // RNE
  return (unsigned short)(u >> 16);
}

__device__ __forceinline__ void gl_lds16(const void* g, void* l) {
  __builtin_amdgcn_global_load_lds((const __attribute__((address_space(1))) void*)g,
                                   (__attribute__((address_space(3))) void*)l,
                                   16, 0, 0);
}

// ---------------- fused fp32 -> bf16 conversion (6 weight tensors) ----------------
static constexpr int D0 = 1048576;            // dyn_gate (8*512*1024/4)
static constexpr int D1 = D0 + 1048576;       // dyn_up
static constexpr int D2 = D1 + 1048576;       // dyn_down
static constexpr int D3 = D2 + 524288;        // sh_gate  (2048*1024/4)
static constexpr int D4 = D3 + 524288;        // sh_up
static constexpr int D5 = D4 + 524288;        // sh_down
__global__ void cvt_all_kernel(const float4* __restrict__ s1,
                               const float4* __restrict__ s2, const float4* __restrict__ s3,
                               const float4* __restrict__ s4, const float4* __restrict__ s5,
                               const float4* __restrict__ s6,
                               ushort4* __restrict__ d1,
                               ushort4* __restrict__ d2, ushort4* __restrict__ d3,
                               ushort4* __restrict__ d4, ushort4* __restrict__ d5,
                               ushort4* __restrict__ d6) {
  int stride = gridDim.x * blockDim.x;
  for (int i = blockIdx.x * blockDim.x + threadIdx.x; i < D5; i += stride) {
    const float4* s; ushort4* d; int off;
    if      (i < D0) { s = s1; d = d1; off = i; }
    else if (i < D1) { s = s2; d = d2; off = i - D0; }
    else if (i < D2) { s = s3; d = d3; off = i - D1; }
    else if (i < D3) { s = s4; d = d4; off = i - D2; }
    else if (i < D4) { s = s5; d = d5; off = i - D3; }
    else             { s = s6; d = d6; off = i - D4; }
    float4 f = s[off];
    d[off] = make_ushort4(f2bf(f.x), f2bf(f.y), f2bf(f.z), f2bf(f.w));
  }
}

// ---------------- gating logits + routing + x->bf16 (fused) ----------------
__global__ __launch_bounds__(256)
void logits_routing_kernel(const float* __restrict__ x, const float* __restrict__ gw,
                           unsigned short* __restrict__ xb,
                           float* __restrict__ logits, float* __restrict__ rw,
                           int* __restrict__ mask) {
  int wave = threadIdx.x >> 6, lane = threadIdx.x & 63;
  int t = blockIdx.x * 4 + wave;
  if (t >= T_TOK) return;
  const float* xr = x + (size_t)t * HDIM;
  float acc[NEXP];
#pragma unroll
  for (int e = 0; e < NEXP; ++e) acc[e] = 0.f;
#pragma unroll
  for (int half = 0; half < 2; ++half) {
    const int h0 = half * 512 + lane * 8;
    float4 a = *(const float4*)(xr + h0);
    float4 b = *(const float4*)(xr + h0 + 4);
    float v[8] = {a.x, a.y, a.z, a.w, b.x, b.y, b.z, b.w};
    union { unsigned short us[8]; uint4 u4; } pk;
#pragma unroll
    for (int j = 0; j < 8; ++j) pk.us[j] = f2bf(v[j]);
    *(uint4*)(xb + (size_t)t * HDIM + h0) = pk.u4;   // coalesced 16B/lane
#pragma unroll
    for (int e = 0; e < NEXP; ++e) {
      float s = 0.f;
#pragma unroll
      for (int j = 0; j < 8; ++j) s += v[j] * gw[e * HDIM + h0 + j];
      acc[e] += s;
    }
  }
#pragma unroll
  for (int e = 0; e < NEXP; ++e) {
    float v = acc[e];
#pragma unroll
    for (int off = 32; off > 0; off >>= 1) v += __shfl_down(v, off, 64);
    acc[e] = v;
  }
  if (lane != 0) return;
  float s[EDYN];
#pragma unroll
  for (int e = 0; e < NEXP; ++e) logits[t * NEXP + e] = acc[e];
#pragma unroll
  for (int e = 0; e < EDYN; ++e) s[e] = acc[e];

  float m = s[0];
#pragma unroll
  for (int e = 1; e < EDYN; ++e) m = fmaxf(m, s[e]);
  float p[EDYN]; float psum = 0.f;
#pragma unroll
  for (int e = 0; e < EDYN; ++e) { p[e] = expf(s[e] - m); psum += p[e]; }
#pragma unroll
  for (int e = 0; e < EDYN; ++e) p[e] /= psum;
  float sp[EDYN];
#pragma unroll
  for (int e = 0; e < EDYN; ++e) sp[e] = p[e];
  for (int i = 1; i < EDYN; ++i) {            // insertion sort descending
    float key = sp[i]; int j = i - 1;
    while (j >= 0 && sp[j] < key) { sp[j + 1] = sp[j]; --j; }
    sp[j + 1] = key;
  }
  float c = 0.f; int cnt = 0;
#pragma unroll
  for (int e = 0; e < EDYN; ++e) { c += sp[e]; cnt += (c < 0.75f) ? 1 : 0; }
  int dyn_k = cnt + 1; if (dyn_k > 4) dyn_k = 4;

  float ms[EDYN];
#pragma unroll
  for (int e = 0; e < EDYN; ++e) ms[e] = s[e];
  float mult[4]; int sel[4];
  for (int k = 0; k < 4; ++k) {
    float thr = ms[0]; int am = 0;
#pragma unroll
    for (int e = 1; e < EDYN; ++e) if (ms[e] > thr) { thr = ms[e]; am = e; }
    float vals[EDYN]; float mx = -INFINITY;
#pragma unroll
    for (int e = 0; e < EDYN; ++e) {
      float factor = fmaxf(fabsf(s[e]), fabsf(thr));
      float ratio = (thr - s[e]) / factor;          // NaN (0/0) compares false
      float v = (ratio > 0.2f) ? -INFINITY : ms[e];
      vals[e] = v; mx = fmaxf(mx, v);
    }
    float sum = 0.f;
#pragma unroll
    for (int e = 0; e < EDYN; ++e) sum += expf(vals[e] - mx);
    mult[k] = expf(vals[am] - mx) / sum;
    sel[k] = am;
    ms[am] = -INFINITY;
  }
  float r[EDYN];
#pragma unroll
  for (int e = 0; e < EDYN; ++e) r[e] = 0.f;
  for (int k = 0; k < 4; ++k) if (k < dyn_k) r[sel[k]] += mult[k];
  float ssum = 0.f;
#pragma unroll
  for (int e = 0; e < EDYN; ++e) ssum += r[e];
#pragma unroll
  for (int e = 0; e < EDYN; ++e) {
    float v = r[e] / ssum;
    rw[t * EDYN + e] = v;
    mask[t * EDYN + e] = (v > 0.f) ? 1 : 0;
  }
}

// ---------------- capacity: parallel prefix-scan per expert + inverse slot map ----------------
__global__ __launch_bounds__(1024)
void capacity_kernel(int* __restrict__ mask, int* __restrict__ tok,
                     int* __restrict__ slot, int* __restrict__ counts) {
  const int e = blockIdx.x;
  const int tid = threadIdx.x;
  const int lane = tid & 63, wave = tid >> 6;
  __shared__ int wsum[16];
  const int t0 = tid * 4;
  int bits[4]; int c = 0;
#pragma unroll
  for (int j = 0; j < 4; ++j) { bits[j] = mask[(t0 + j) * EDYN + e]; c += bits[j]; }
  int sc = c;                                  // inclusive wave scan
#pragma unroll
  for (int off = 1; off < 64; off <<= 1) {
    int v = __shfl_up(sc, off, 64);
    if (lane >= off) sc += v;
  }
  if (lane == 63) wsum[wave] = sc;
  __syncthreads();
  int wbase = 0;
  for (int w = 0; w < wave; ++w) wbase += wsum[w];
  int pos = wbase + sc - c;                    // exclusive prefix (token order)
#pragma unroll
  for (int j = 0; j < 4; ++j) {
    int keep = bits[j] && (pos < CAPE);
    if (keep) tok[e * CAPE + pos] = t0 + j;
    mask[(t0 + j) * EDYN + e] = keep;
    slot[(t0 + j) * EDYN + e] = keep ? pos : -1;
    pos += bits[j];
  }
  int total = 0;
  for (int w = 0; w < 16; ++w) total += wsum[w];
  int cnt = total < CAPE ? total : CAPE;
  if (tid == 0) counts[e] = cnt;
  for (int r = cnt + tid; r < CAPE; r += 1024) tok[e * CAPE + r] = -1;  // pad sentinel
}

// ---------------- final gate ----------------
__global__ __launch_bounds__(256)
void final_gate_kernel(const float* __restrict__ logits, const int* __restrict__ mask,
                       const float* __restrict__ rw, float* __restrict__ gdyn,
                       float* __restrict__ wsh) {
  int t = blockIdx.x * blockDim.x + threadIdx.x;
  if (t >= T_TOK) return;
  float vals[NEXP]; float mx = -INFINITY;
  int mk[EDYN];
#pragma unroll
  for (int e = 0; e < EDYN; ++e) {
    mk[e] = mask[t * EDYN + e];
    vals[e] = mk[e] ? logits[t * NEXP + e] : -INFINITY;
    mx = fmaxf(mx, vals[e]);
  }
  vals[EDYN] = logits[t * NEXP + EDYN];
  mx = fmaxf(mx, vals[EDYN]);
  float ex[NEXP]; float sum = 0.f;
#pragma unroll
  for (int e = 0; e < NEXP; ++e) { ex[e] = expf(vals[e] - mx); sum += ex[e]; }
  float inv = 1.f / sum;
  float sd = 0.f;
#pragma unroll
  for (int e = 0; e < EDYN; ++e) sd += ex[e] * inv;
#pragma unroll
  for (int e = 0; e < EDYN; ++e)
    gdyn[t * EDYN + e] = mk[e] ? rw[t * EDYN + e] * sd : 0.f;
  wsh[t] = ex[EDYN] * inv;
}

// ---------------- shared gate+up: 256x(128+128) tile, 4-phase counted-vmcnt ----------------
__global__ __launch_bounds__(512, 2)
void gemm_gateup_8ph(const unsigned short* __restrict__ xb,
                     const unsigned short* __restrict__ Wg,
                     const unsigned short* __restrict__ Wu,
                     unsigned short* __restrict__ act) {
  extern __shared__ char lds[];
  constexpr int NT = HDIM / 64;          // 16 K-tiles
  const int tid  = threadIdx.x;
  const int lane = tid & 63;
  const int wid  = tid >> 6;
  const int wrh  = wid >> 2;             // 0..1  M-half (128 rows each)
  const int wc   = wid & 3;              // 0..3  N-quarter (32 cols each)
  const int m0 = (blockIdx.x & 15) * 256;
  const int n0 = (blockIdx.x >> 4) * 128;

  const int srow = wid * 16 + (lane >> 2);               // 0..127
  const int sb9  = (lane >> 5) & 1;                      // row bit3
  const int scl  = ((lane & 3) << 4) ^ (sb9 << 5);       // inverse-swizzled col byte
  const char* sA0 = (const char*)xb + (size_t)(m0 + srow) * 2048 + scl;
  const char* sA1 = sA0 + (size_t)128 * 2048;
  const char* sBg = (const char*)Wg + (size_t)(n0 + srow) * 2048 + scl;
  const char* sBu = (const char*)Wu + (size_t)(n0 + srow) * 2048 + scl;
  const int ldsW = wid * 1024;                           // wave chunk in half-tile

  const int rl  = lane & 15;
  const int swz = ((lane >> 4) << 4) ^ ((rl & 8) << 2);  // kc ^ bankfix
  const int aRd = wrh * 16384 + rl * 64 + swz;
  const int bRd = wc * 2048 + rl * 64 + swz;

  f32x4 accg[8][2], accu[8][2];
#pragma unroll
  for (int i = 0; i < 8; ++i)
#pragma unroll
    for (int j = 0; j < 2; ++j) {
      f32x4 z = {0.f, 0.f, 0.f, 0.f};
      accg[i][j] = z; accu[i][j] = z;
    }
  bf16x8 aF[2][4][2];   // [h][rf][ks]
  bf16x8 bF[2][2];      // [cf][ks]

#define STAGE8(srcp, regoff)                                               \
  if (ktN < NT) {                                                          \
    gl_lds16((srcp) + (size_t)ktN * 128,       lds + nxt * 65536 + (regoff) + ldsW);          \
    gl_lds16((srcp) + (size_t)ktN * 128 + 64,  lds + nxt * 65536 + (regoff) + 8192 + ldsW);   \
  }
#define LOAD_A8(h)                                                         \
  _Pragma("unroll") for (int rf = 0; rf < 4; ++rf)                         \
  _Pragma("unroll") for (int ks = 0; ks < 2; ++ks)                         \
    aF[h][rf][ks] = *reinterpret_cast<const bf16x8*>(                      \
      lds + cur * 65536 + aRd + ks * 8192 + (h) * 4096 + rf * 1024);
#define LOAD_B8(off)                                                       \
  _Pragma("unroll") for (int cf = 0; cf < 2; ++cf)                         \
  _Pragma("unroll") for (int ks = 0; ks < 2; ++ks)                         \
    bF[cf][ks] = *reinterpret_cast<const bf16x8*>(                         \
      lds + cur * 65536 + (off) + bRd + ks * 8192 + cf * 1024);
#define MFMA_PH8(h, ACC)                                                   \
  __builtin_amdgcn_s_setprio(1);                                           \
  _Pragma("unroll") for (int rf = 0; rf < 4; ++rf)                         \
  _Pragma("unroll") for (int cf = 0; cf < 2; ++cf)                         \
  _Pragma("unroll") for (int ks = 0; ks < 2; ++ks)                         \
    ACC[(h) * 4 + rf][cf] = __builtin_amdgcn_mfma_f32_16x16x32_bf16(       \
        aF[h][rf][ks], bF[cf][ks], ACC[(h) * 4 + rf][cf], 0, 0, 0);        \
  __builtin_amdgcn_s_setprio(0);
#define BAR8() __builtin_amdgcn_sched_barrier(0);                          \
               __builtin_amdgcn_s_barrier();                               \
               __builtin_amdgcn_sched_barrier(0);

  {
    const int ktN = 0, nxt = 0;
    STAGE8(sA0, 0) STAGE8(sA1, 16384) STAGE8(sBg, 32768) STAGE8(sBu, 49152)
  }
  asm volatile("s_waitcnt vmcnt(0)" ::: "memory");
  BAR8()

  for (int j = 0; j < NT; ++j) {
    const int cur = j & 1, nxt = cur ^ 1, ktN = j + 1;
    STAGE8(sA0, 0)
    LOAD_A8(0)
    LOAD_B8(32768)
    MFMA_PH8(0, accg)
    BAR8()
    STAGE8(sA1, 16384)
    LOAD_A8(1)
    MFMA_PH8(1, accg)
    asm volatile("s_waitcnt vmcnt(4)" ::: "memory");   // prev Bu landed
    BAR8()
    STAGE8(sBg, 32768)
    LOAD_B8(49152)
    MFMA_PH8(0, accu)
    BAR8()
    STAGE8(sBu, 49152)
    MFMA_PH8(1, accu)
    asm volatile("s_waitcnt vmcnt(2)" ::: "memory");   // next A0/A1/Bg landed
    BAR8()
  }

#pragma unroll
  for (int rf = 0; rf < 8; ++rf)
#pragma unroll
    for (int cf = 0; cf < 2; ++cf)
#pragma unroll
      for (int jj = 0; jj < 4; ++jj) {
        int row = m0 + wrh * 128 + (rf >> 2) * 64 + (rf & 3) * 16 + ((lane >> 4) << 2) + jj;
        int col = n0 + wc * 32 + cf * 16 + (lane & 15);
        float g = accg[rf][cf][jj], u = accu[rf][cf][jj];
        float v = (g / (1.f + __expf(-g))) * u;   // silu(g)*u
        act[(size_t)row * IFIX_ + col] = f2bf(v);
      }
#undef STAGE8
#undef LOAD_A8
#undef LOAD_B8
#undef MFMA_PH8
#undef BAR8
}

// ---------------- dyn gate+up GEMM (gathered), 2-phase 128x64x2 ----------------
__global__ __launch_bounds__(256)
void gemm_gateup_dyn(const unsigned short* __restrict__ xb,
                     const unsigned short* __restrict__ Wg,
                     const unsigned short* __restrict__ Wu,
                     unsigned short* __restrict__ act,
                     const int* __restrict__ toklist,
                     const int* __restrict__ counts,
                     int N, int K, int Mstride, int MT) {
  const int e = blockIdx.z;
  const int nid = blockIdx.x;
  const int m0 = (nid % MT) * 128;
  const int n0 = (nid / MT) * 64;
  if (m0 >= counts[e]) return;

  const unsigned short* Wg_e = Wg + (size_t)e * N * K;
  const unsigned short* Wu_e = Wu + (size_t)e * N * K;
  unsigned short* act_e = act + (size_t)e * Mstride * N;
  const int* tok_e = toklist + e * CAPE;

  __shared__ __align__(16) unsigned short As[128 * 64];
  __shared__ __align__(16) unsigned short Bgs[64 * 64];
  __shared__ __align__(16) unsigned short Bus[64 * 64];

  const int tid = threadIdx.x;
  const int lane = tid & 63;
  const int wave = tid >> 6;
  const int wr = wave >> 1, wc = wave & 1;
  const int srow = tid >> 3;
  const int scol = (tid & 7) * 8;

  const unsigned short* a_src[4];
#pragma unroll
  for (int it = 0; it < 4; ++it) {
    int r = m0 + it * 32 + srow;
    int tv = tok_e[r];
    a_src[it] = xb + (size_t)(tv < 0 ? 0 : tv) * K + scol;
  }
  const unsigned short* bg_src[2]; const unsigned short* bu_src[2];
#pragma unroll
  for (int it = 0; it < 2; ++it) {
    int r = n0 + it * 32 + srow;
    bg_src[it] = Wg_e + (size_t)r * K + scol;
    bu_src[it] = Wu_e + (size_t)r * K + scol;
  }

  f32x4 accg[4][2], accu[4][2];
#pragma unroll
  for (int i = 0; i < 4; ++i)
#pragma unroll
    for (int j = 0; j < 2; ++j) {
      f32x4 z = {0.f, 0.f, 0.f, 0.f};
      accg[i][j] = z; accu[i][j] = z;
    }

  for (int kt = 0; kt < K; kt += 64) {
#pragma unroll
    for (int it = 0; it < 4; ++it)
      gl_lds16(a_src[it] + kt, &As[it * 2048 + wave * 512]);
#pragma unroll
    for (int it = 0; it < 2; ++it) {
      gl_lds16(bg_src[it] + kt, &Bgs[it * 2048 + wave * 512]);
      gl_lds16(bu_src[it] + kt, &Bus[it * 2048 + wave * 512]);
    }
    __syncthreads();
#pragma unroll
    for (int kk = 0; kk < 2; ++kk) {
      const int ko = kk * 32 + (lane >> 4) * 8;
      bf16x8 a[4], bg[2], bu[2];
#pragma unroll
      for (int mi = 0; mi < 4; ++mi)
        a[mi] = *reinterpret_cast<const bf16x8*>(&As[(wr * 64 + mi * 16 + (lane & 15)) * 64 + ko]);
#pragma unroll
      for (int ni = 0; ni < 2; ++ni) {
        bg[ni] = *reinterpret_cast<const bf16x8*>(&Bgs[(wc * 32 + ni * 16 + (lane & 15)) * 64 + ko]);
        bu[ni] = *reinterpret_cast<const bf16x8*>(&Bus[(wc * 32 + ni * 16 + (lane & 15)) * 64 + ko]);
      }
#pragma unroll
      for (int mi = 0; mi < 4; ++mi)
#pragma unroll
        for (int ni = 0; ni < 2; ++ni) {
          accg[mi][ni] = __builtin_amdgcn_mfma_f32_16x16x32_bf16(a[mi], bg[ni], accg[mi][ni], 0, 0, 0);
          accu[mi][ni] = __builtin_amdgcn_mfma_f32_16x16x32_bf16(a[mi], bu[ni], accu[mi][ni], 0, 0, 0);
        }
    }
    __syncthreads();
  }

#pragma unroll
  for (int mi = 0; mi < 4; ++mi)
#pragma unroll
    for (int ni = 0; ni < 2; ++ni)
#pragma unroll
      for (int j = 0; j < 4; ++j) {
        int row = m0 + wr * 64 + mi * 16 + (lane >> 4) * 4 + j;
        int col = n0 + wc * 32 + ni * 16 + (lane & 15);
        float g = accg[mi][ni][j], u = accu[mi][ni][j];
        float v = (g / (1.f + __expf(-g))) * u;   // silu(g)*u
        act_e[(size_t)row * N + col] = f2bf(v);
      }
}

// ---------------- shared down GEMM (2-phase), stores wsh*v to out ----------------
__global__ __launch_bounds__(256)
void gemm_down_sh(const unsigned short* __restrict__ act,
                  const unsigned short* __restrict__ Wd,
                  float* __restrict__ out,
                  const float* __restrict__ wsh,
                  int N, int K, int MT) {
  const int nid = blockIdx.x;
  const int m0 = (nid % MT) * 128;
  const int n0 = (nid / MT) * 128;

  __shared__ __align__(16) unsigned short As[128 * 64];
  __shared__ __align__(16) unsigned short Bs[128 * 64];

  const int tid = threadIdx.x;
  const int lane = tid & 63;
  const int wave = tid >> 6;
  const int wr = wave >> 1, wc = wave & 1;
  const int srow = tid >> 3;
  const int scol = (tid & 7) * 8;

  const unsigned short* a_src[4]; const unsigned short* b_src[4];
#pragma unroll
  for (int it = 0; it < 4; ++it) {
    a_src[it] = act + (size_t)(m0 + it * 32 + srow) * K + scol;
    b_src[it] = Wd + (size_t)(n0 + it * 32 + srow) * K + scol;
  }

  f32x4 acc[4][4];
#pragma unroll
  for (int i = 0; i < 4; ++i)
#pragma unroll
    for (int j = 0; j < 4; ++j) { f32x4 z = {0.f, 0.f, 0.f, 0.f}; acc[i][j] = z; }

  for (int kt = 0; kt < K; kt += 64) {
#pragma unroll
    for (int it = 0; it < 4; ++it) {
      gl_lds16(a_src[it] + kt, &As[it * 2048 + wave * 512]);
      gl_lds16(b_src[it] + kt, &Bs[it * 2048 + wave * 512]);
    }
    __syncthreads();
#pragma unroll
    for (int kk = 0; kk < 2; ++kk) {
      const int ko = kk * 32 + (lane >> 4) * 8;
      bf16x8 a[4], b[4];
#pragma unroll
      for (int mi = 0; mi < 4; ++mi)
        a[mi] = *reinterpret_cast<const bf16x8*>(&As[(wr * 64 + mi * 16 + (lane & 15)) * 64 + ko]);
#pragma unroll
      for (int ni = 0; ni < 4; ++ni)
        b[ni] = *reinterpret_cast<const bf16x8*>(&Bs[(wc * 64 + ni * 16 + (lane & 15)) * 64 + ko]);
#pragma unroll
      for (int mi = 0; mi < 4; ++mi)
#pragma unroll
        for (int ni = 0; ni < 4; ++ni)
          acc[mi][ni] = __builtin_amdgcn_mfma_f32_16x16x32_bf16(a[mi], b[ni], acc[mi][ni], 0, 0, 0);
    }
    __syncthreads();
  }

#pragma unroll
  for (int mi = 0; mi < 4; ++mi)
#pragma unroll
    for (int ni = 0; ni < 4; ++ni)
#pragma unroll
      for (int j = 0; j < 4; ++j) {
        int row = m0 + wr * 64 + mi * 16 + (lane >> 4) * 4 + j;
        int col = n0 + wc * 64 + ni * 16 + (lane & 15);
        out[(size_t)row * HDIM + col] = wsh[row] * acc[mi][ni][j];
      }
}

// ---------------- dyn down GEMM: plain stores to ydyn scratch (no atomics) ----------------
__global__ __launch_bounds__(256)
void gemm_down_dyn(const unsigned short* __restrict__ act,
                   const unsigned short* __restrict__ Wd,
                   float* __restrict__ ydyn,
                   const int* __restrict__ counts,
                   int N, int K, int MT) {
  const int e = blockIdx.z;
  const int nid = blockIdx.x;
  const int m0 = (nid % MT) * 128;
  const int n0 = (nid / MT) * 128;
  if (m0 >= counts[e]) return;

  const unsigned short* A_e = act + (size_t)e * CAPE * K;
  const unsigned short* Wd_e = Wd + (size_t)e * N * K;
  float* y_e = ydyn + (size_t)e * CAPE * HDIM;

  __shared__ __align__(16) unsigned short As[128 * 64];
  __shared__ __align__(16) unsigned short Bs[128 * 64];

  const int tid = threadIdx.x;
  const int lane = tid & 63;
  const int wave = tid >> 6;
  const int wr = wave >> 1, wc = wave & 1;
  const int srow = tid >> 3;
  const int scol = (tid & 7) * 8;

  const unsigned short* a_src[4]; const unsigned short* b_src[4];
#pragma unroll
  for (int it = 0; it < 4; ++it) {
    a_src[it] = A_e + (size_t)(m0 + it * 32 + srow) * K + scol;
    b_src[it] = Wd_e + (size_t)(n0 + it * 32 + srow) * K + scol;
  }

  f32x4 acc[4][4];
#pragma unroll
  for (int i = 0; i < 4; ++i)
#pragma unroll
    for (int j = 0; j < 4; ++j) { f32x4 z = {0.f, 0.f, 0.f, 0.f}; acc[i][j] = z; }

  for (int kt = 0; kt < K; kt += 64) {
#pragma unroll
    for (int it = 0; it < 4; ++it) {
      gl_lds16(a_src[it] + kt, &As[it * 2048 + wave * 512]);
      gl_lds16(b_src[it] + kt, &Bs[it * 2048 + wave * 512]);
    }
    __syncthreads();
#pragma unroll
    for (int kk = 0; kk < 2; ++kk) {
      const int ko = kk * 32 + (lane >> 4) * 8;
      bf16x8 a[4], b[4];
#pragma unroll
      for (int mi = 0; mi < 4; ++mi)
        a[mi] = *reinterpret_cast<const bf16x8*>(&As[(wr * 64 + mi * 16 + (lane & 15)) * 64 + ko]);
#pragma unroll
      for (int ni = 0; ni < 4; ++ni)
        b[ni] = *reinterpret_cast<const bf16x8*>(&Bs[(wc * 64 + ni * 16 + (lane & 15)) * 64 + ko]);
#pragma unroll
      for (int mi = 0; mi < 4; ++mi)
#pragma unroll
        for (int ni = 0; ni < 4; ++ni)
          acc[mi][ni] = __builtin_amdgcn_mfma_f32_16x16x32_bf16(a[mi], b[ni], acc[mi][ni], 0, 0, 0);
    }
    __syncthreads();
  }

#pragma unroll
  for (int mi = 0; mi < 4; ++mi)
#pragma unroll
    for (int ni = 0; ni < 4; ++ni)
#pragma unroll
      for (int j = 0; j < 4; ++j) {
        int row = m0 + wr * 64 + mi * 16 + (lane >> 4) * 4 + j;
        int col = n0 + wc * 64 + ni * 16 + (lane & 15);
        y_e[(size_t)row * HDIM + col] = acc[mi][ni][j];
      }
}

// ---------------- gather: out[t] += sum_e gdyn[t][e] * ydyn[e][slot[t][e]] ----------------
// one block per token; 256 thr x float4 = 1024 cols; race-free RMW.
__global__ __launch_bounds__(256)
void gather_kernel(const float* __restrict__ ydyn, const int* __restrict__ slot,
                   const float* __restrict__ gdyn, float* __restrict__ out) {
  const int t = blockIdx.x;
  const int c = threadIdx.x * 4;
  float4 v = *(float4*)&out[(size_t)t * HDIM + c];
#pragma unroll
  for (int e = 0; e < EDYN; ++e) {
    int s = slot[t * EDYN + e];
    if (s >= 0) {
      float g = gdyn[t * EDYN + e];
      float4 y = *(const float4*)&ydyn[((size_t)e * CAPE + s) * HDIM + c];
      v.x += g * y.x; v.y += g * y.y; v.z += g * y.z; v.w += g * y.w;
    }
  }
  *(float4*)&out[(size_t)t * HDIM + c] = v;
}

// ---------------- host ----------------
extern "C" void kernel_launch(void* const* d_in, const int* in_sizes, int n_in,
                              void* d_out, int out_size, void* d_ws, size_t ws_size,
                              hipStream_t stream) {
  const float* x   = (const float*)d_in[0];
  const float* gw  = (const float*)d_in[1];
  const float* wdg = (const float*)d_in[2];
  const float* wdu = (const float*)d_in[3];
  const float* wdd = (const float*)d_in[4];
  const float* wsg = (const float*)d_in[5];
  const float* wsu = (const float*)d_in[6];
  const float* wsd = (const float*)d_in[7];
  float* out = (float*)d_out;

  char* p = (char*)d_ws;
  auto alloc = [&](size_t bytes) {
    char* r = p; p += (bytes + 255) & ~(size_t)255; return r;
  };
  unsigned short* xb    = (unsigned short*)alloc((size_t)T_TOK * HDIM * 2);
  unsigned short* wdgb  = (unsigned short*)alloc((size_t)EDYN * IDYN_ * HDIM * 2);
  unsigned short* wdub  = (unsigned short*)alloc((size_t)EDYN * IDYN_ * HDIM * 2);
  unsigned short* wddb  = (unsigned short*)alloc((size_t)EDYN * HDIM * IDYN_ * 2);
  unsigned short* wsgb  = (unsigned short*)alloc((size_t)IFIX_ * HDIM * 2);
  unsigned short* wsub  = (unsigned short*)alloc((size_t)IFIX_ * HDIM * 2);
  unsigned short* wsdb  = (unsigned short*)alloc((size_t)HDIM * IFIX_ * 2);
  unsigned short* actsh = (unsigned short*)alloc((size_t)T_TOK * IFIX_ * 2);
  unsigned short* actdy = (unsigned short*)alloc((size_t)EDYN * CAPE * IDYN_ * 2);
  float* ydyn   = (float*)alloc((size_t)EDYN * CAPE * HDIM * 4);
  float* logits = (float*)alloc((size_t)T_TOK * NEXP * 4);
  float* rw     = (float*)alloc((size_t)T_TOK * EDYN * 4);
  int*   mask   = (int*)alloc((size_t)T_TOK * EDYN * 4);
  int*   slot   = (int*)alloc((size_t)T_TOK * EDYN * 4);
  float* gdyn   = (float*)alloc((size_t)T_TOK * EDYN * 4);
  float* wshv   = (float*)alloc((size_t)T_TOK * 4);
  int*   counts = (int*)alloc(256);
  int*   tok    = (int*)alloc((size_t)EDYN * CAPE * 4);

  cvt_all_kernel<<<dim3(2048), dim3(256), 0, stream>>>(
      (const float4*)wdg, (const float4*)wdu, (const float4*)wdd,
      (const float4*)wsg, (const float4*)wsu, (const float4*)wsd,
      (ushort4*)wdgb, (ushort4*)wdub, (ushort4*)wddb,
      (ushort4*)wsgb, (ushort4*)wsub, (ushort4*)wsdb);

  logits_routing_kernel<<<dim3(T_TOK / 4), dim3(256), 0, stream>>>(x, gw, xb, logits, rw, mask);
  capacity_kernel<<<dim3(EDYN), dim3(1024), 0, stream>>>(mask, tok, slot, counts);
  final_gate_kernel<<<dim3(T_TOK / 256), dim3(256), 0, stream>>>(logits, mask, rw, gdyn, wshv);

  // shared expert
  gemm_gateup_8ph<<<dim3(256), dim3(512), 131072, stream>>>(xb, wsgb, wsub, actsh);
  gemm_down_sh<<<dim3((T_TOK / 128) * (HDIM / 128), 1, 1), dim3(256), 0, stream>>>(
      actsh, wsdb, out, wshv, HDIM, IFIX_, T_TOK / 128);
  // dyn experts -> ydyn scratch (no atomics), then per-token gather
  gemm_gateup_dyn<<<dim3((CAPE / 128) * (IDYN_ / 64), 1, EDYN), dim3(256), 0, stream>>>(
      xb, wdgb, wdub, actdy, tok, counts, IDYN_, HDIM, CAPE, CAPE / 128);
  gemm_down_dyn<<<dim3((CAPE / 128) * (HDIM / 128), 1, EDYN), dim3(256), 0, stream>>>(
      actdy, wddb, ydyn, counts, HDIM, IDYN_, CAPE / 128);
  gather_kernel<<<dim3(T_TOK), dim3(256), 0, stream>>>(ydyn, slot, gdyn, out);
}